// Round 9
// baseline (3765.886 us; speedup 1.0000x reference)
//
#include <hip/hip_runtime.h>

#define HW 16384
#define BATCH 8

typedef unsigned short u16;
typedef __attribute__((ext_vector_type(8))) short bfrag;   // 8 bf16 in 4 VGPRs
typedef __attribute__((ext_vector_type(4))) float ffrag;   // MFMA accumulator
typedef __attribute__((ext_vector_type(4))) float f4v;

// ---------------------------------------------------------------------------
__device__ __forceinline__ u16 f2bf(float f) {
  unsigned int u = __float_as_uint(f);
  u += 0x7FFFu + ((u >> 16) & 1u);
  return (u16)(u >> 16);
}
__device__ __forceinline__ float bf2f(u16 h) {
  return __uint_as_float(((unsigned int)h) << 16);
}
__device__ __forceinline__ ffrag mfma16(bfrag a, bfrag b, ffrag c) {
  return __builtin_amdgcn_mfma_f32_16x16x32_bf16(a, b, c, 0, 0, 0);
}

__device__ __forceinline__ float spline_eval(float x, const float* __restrict__ c,
                                             int K, float xmin, float xmax) {
  float step = (xmax - xmin) / (float)(K - 1);
  float t = (x - xmin) / step;
  float fidx = floorf(t);
  fidx = fminf(fmaxf(fidx, 0.0f), (float)(K - 2));
  int idx = (int)fidx;
  float frac = t - fidx;
  return c[idx] * (1.0f - frac) + c[idx + 1] * frac;
}
__device__ __forceinline__ float spline31(float x, const float* __restrict__ c) {
  float t = x * 10.0f;
  float fi = floorf(t);
  fi = fminf(fmaxf(fi, 0.0f), 29.0f);
  int i = (int)fi;
  float fr = t - fi;
  return c[i] * (1.0f - fr) + c[i + 1] * fr;
}

// ---------------------------------------------------------------------------
// Weight prep: OIHW fp32 -> MFMA B-fragment order, bf16 hi/lo planes.
// (verified r4-r8)
// ---------------------------------------------------------------------------
template<int KS, int CIW, int CO, int NTT, int NSLICE, int TAPS, int CHUNKS, bool TR>
__global__ void k_prepw(const float* __restrict__ W, u16* __restrict__ hi,
                        u16* __restrict__ lo) {
  int gid = blockIdx.x * 256 + threadIdx.x;
  const int total = NSLICE * CHUNKS * NTT * 64;
  if (gid >= total) return;
  int L = gid & 63;
  int rest = gid >> 6;
  int ntg = rest % NTT; rest /= NTT;
  int ch = rest % CHUNKS;
  int sl = rest / CHUNKS;
  int q = L >> 4, n = L & 15;
  int tap = ch * 4 + q;
  int co = ntg * 16 + n;
  int dh = tap / KS, dw = tap - dh * KS;
  for (int j = 0; j < 8; ++j) {
    int ci = sl * 8 + j;
    float v = 0.0f;
    if (tap < TAPS && co < CO) {
      if (TR)
        v = W[(((size_t)ci * CO + co) * KS + (KS - 1 - dh)) * KS + (KS - 1 - dw)];
      else
        v = W[(((size_t)co * CIW + ci) * KS + dh) * KS + dw];
    }
    u16 h = f2bf(v);
    hi[(size_t)gid * 8 + j] = h;
    lo[(size_t)gid * 8 + j] = f2bf(v - bf2f(h));
  }
}

// ---------------------------------------------------------------------------
// bconv: LDS-staged, 1-term bf16 MFMA conv (r6/r8-verified) — CG path only.
// EPI 3: v * m^2 -> slice-major bf16 (128ch) | EPI 4: f2bf(v), co<8 -> 8ch
// ---------------------------------------------------------------------------
template<int KS, int SLICES, int TAPS, int CHUNKS, int NT, int NTT, int EPI>
__global__ __launch_bounds__(256) void bconv(
    const u16* __restrict__ in, const u16* __restrict__ wHi,
    u16* __restrict__ outBf, const u16* __restrict__ mskc)
{
  constexpr int P  = KS / 2;
  constexpr int IW = 16 + 2 * P;
  constexpr int IH = 16 + 2 * P;

  __shared__ __align__(16) u16 sA[IH * IW * 8];

  const int tid = threadIdx.x;
  const int wv  = tid >> 6;
  const int L   = tid & 63;
  const int q   = L >> 4;
  const int n16 = L & 15;

  const int tx = blockIdx.x & 7, ty = blockIdx.x >> 3;
  const int w0 = tx * 16, h0 = ty * 16;
  const int bb = blockIdx.y;
  const int bz = blockIdx.z;

  ffrag acc[4][NT];
#pragma unroll
  for (int i = 0; i < 4; ++i)
#pragma unroll
    for (int t = 0; t < NT; ++t) acc[i][t] = (ffrag)0.0f;

  for (int slc = 0; slc < SLICES; ++slc) {
    __syncthreads();
    for (int e = tid; e < IH * IW; e += 256) {
      int ih = e / IW, iw = e - ih * IW;
      int gh = h0 + ih - P, gw = w0 + iw - P;
      f4v v = (f4v)0.0f;
      if (gh >= 0 && gh < 128 && gw >= 0 && gw < 128)
        v = *(const f4v*)(in + (((size_t)(bb * SLICES + slc) * HW) + gh * 128 + gw) * 8);
      *(f4v*)(sA + (size_t)e * 8) = v;
    }
    __syncthreads();

    const u16* wS = wHi + (size_t)slc * CHUNKS * NTT * 512;
    for (int ch = 0; ch < CHUNKS; ++ch) {
      int tap = ch * 4 + q;
      int dh = 0, dw = 0;
      if (tap < TAPS) { dh = tap / KS; dw = tap - dh * KS; }
      int toff = dh * IW + dw;
      bfrag A[4];
#pragma unroll
      for (int i = 0; i < 4; ++i)
        A[i] = *(const bfrag*)(sA + ((wv * 4 + i) * IW + n16 + toff) * 8);
#pragma unroll
      for (int t = 0; t < NT; ++t) {
        bfrag B = *(const bfrag*)(wS + ((size_t)ch * NTT + bz * NT + t) * 512 + L * 8);
#pragma unroll
        for (int i = 0; i < 4; ++i) acc[i][t] = mfma16(A[i], B, acc[i][t]);
      }
    }
  }

#pragma unroll
  for (int i = 0; i < 4; ++i) {
    const int h = h0 + wv * 4 + i;
#pragma unroll
    for (int t = 0; t < NT; ++t) {
      const int co = bz * (NT * 16) + t * 16 + n16;
#pragma unroll
      for (int r = 0; r < 4; ++r) {
        const int w = w0 + q * 4 + r;
        float v = acc[i][t][r];
        if (EPI == 4) {
          if (n16 < 8)
            outBf[((size_t)bb * HW + h * 128 + w) * 8 + n16] = f2bf(v);
        } else if (EPI == 3) {
          size_t o = (((size_t)(bb * 16 + (co >> 3)) * HW) + h * 128 + w) * 8 + (co & 7);
          float m = bf2f(mskc[o]);
          outBf[o] = f2bf(v * m * m);
        }
      }
    }
  }
}

// ---------------------------------------------------------------------------
// mconv (r4/r6/r8-verified): 3-term split MFMA conv, fp32 NHWC in.
// EPI 1: spline31(|v|) -> fp32 NHWC | EPI 2: clip spline -> mask_c bf16
// ---------------------------------------------------------------------------
template<int KS, int CIN, int NSLICE, int TAPS, int CHUNKS,
         int TH, int MTW, int NT, int NTT, int EPI>
__global__ __launch_bounds__(256) void mconv(
    const float* __restrict__ inF,
    const u16* __restrict__ wHi, const u16* __restrict__ wLo,
    float* __restrict__ outF, u16* __restrict__ outBf,
    const float* __restrict__ sp, const float* __restrict__ sl,
    int binOfs, int boutOfs)
{
  constexpr int P  = KS / 2;
  constexpr int IW = 16 + 2 * P;
  constexpr int IH = TH + 2 * P;

  __shared__ __align__(16) u16 sHi[IH * IW * 8];
  __shared__ __align__(16) u16 sLo[IH * IW * 8];

  const int tid = threadIdx.x;
  const int wv  = tid >> 6;
  const int L   = tid & 63;
  const int q   = L >> 4;
  const int n16 = L & 15;

  const int tx = blockIdx.x & 7;
  const int ty = blockIdx.x >> 3;
  const int w0 = tx * 16, h0 = ty * TH;
  const int bin  = (int)blockIdx.y + binOfs;
  const int bout = (int)blockIdx.y + boutOfs;
  const int bz = blockIdx.z;

  ffrag acc[MTW][NT];
#pragma unroll
  for (int i = 0; i < MTW; ++i)
#pragma unroll
    for (int t = 0; t < NT; ++t) acc[i][t] = (ffrag)0.0f;

  for (int slc = 0; slc < NSLICE; ++slc) {
    __syncthreads();
    for (int e = tid; e < IH * IW; e += 256) {
      int ih = e / IW, iw = e - ih * IW;
      int gh = h0 + ih - P, gw = w0 + iw - P;
      float v[8];
      if (gh >= 0 && gh < 128 && gw >= 0 && gw < 128) {
        const float* s = inF + (((size_t)(bin * 128 + gh) * 128 + gw) * CIN + slc * 8);
        f4v a = *(const f4v*)s;
        f4v b2 = *(const f4v*)(s + 4);
        v[0] = a[0]; v[1] = a[1]; v[2] = a[2]; v[3] = a[3];
        v[4] = b2[0]; v[5] = b2[1]; v[6] = b2[2]; v[7] = b2[3];
      } else {
#pragma unroll
        for (int j = 0; j < 8; ++j) v[j] = 0.0f;
      }
#pragma unroll
      for (int j = 0; j < 8; ++j) {
        u16 hb = f2bf(v[j]);
        sHi[e * 8 + j] = hb;
        sLo[e * 8 + j] = f2bf(v[j] - bf2f(hb));
      }
    }
    __syncthreads();

    const u16* wHs = wHi + (size_t)slc * CHUNKS * NTT * 512;
    const u16* wLs = wLo + (size_t)slc * CHUNKS * NTT * 512;
    for (int ch = 0; ch < CHUNKS; ++ch) {
      int tap = ch * 4 + q;
      int dh = tap / KS;
      int dw = tap - dh * KS;
      int toff = (tap < TAPS) ? (dh * IW + dw) : 0;
      bfrag Ah[MTW], Al[MTW];
#pragma unroll
      for (int i = 0; i < MTW; ++i) {
        int a8 = ((wv * MTW + i) * IW + n16 + toff) * 8;
        Ah[i] = *(const bfrag*)(sHi + a8);
        Al[i] = *(const bfrag*)(sLo + a8);
      }
#pragma unroll
      for (int t = 0; t < NT; ++t) {
        size_t off = ((size_t)ch * NTT + bz * NT + t) * 512 + L * 8;
        bfrag Bh = *(const bfrag*)(wHs + off);
        bfrag Bl = *(const bfrag*)(wLs + off);
#pragma unroll
        for (int i = 0; i < MTW; ++i) {
          acc[i][t] = mfma16(Ah[i], Bh, acc[i][t]);
          acc[i][t] = mfma16(Ah[i], Bl, acc[i][t]);
          acc[i][t] = mfma16(Al[i], Bh, acc[i][t]);
        }
      }
    }
  }

#pragma unroll
  for (int i = 0; i < MTW; ++i) {
    const int h = h0 + wv * MTW + i;
#pragma unroll
    for (int t = 0; t < NT; ++t) {
      const int co = bz * (NT * 16) + t * 16 + n16;
#pragma unroll
      for (int r = 0; r < 4; ++r) {
        const int w = w0 + q * 4 + r;
        float v = acc[i][t][r];
        if (EPI == 1) {
          outF[(((size_t)bout * 128 + h) * 128 + w) * 128 + co] = spline31(fabsf(v), sp);
        } else if (EPI == 2) {
          float s = sl[bout * 128 + co];
          float x = spline31(s * fabsf(v), sp);
          x = fminf(fmaxf(x, 0.01f), 1.0f);
          size_t o = (((size_t)(bout * 16 + (co >> 3)) * HW) + h * 128 + w) * 8 + (co & 7);
          outBf[o] = f2bf(x);
        }
      }
    }
  }
}

// ---------------------------------------------------------------------------
// fused forward 1->4->8 (r5-r8 verified). OUT 0: fp32 NHWC8 | OUT 1: bf16 8ch
// ---------------------------------------------------------------------------
template<int OUT>
__global__ __launch_bounds__(256) void fused_fwd(
    const float* __restrict__ in, const float* __restrict__ wA,
    const float* __restrict__ wB, float* __restrict__ outF,
    u16* __restrict__ outBf)
{
  __shared__ float sX[32 * 48];
  __shared__ float sT4[4][24 * 41];
  __shared__ float sWA[81 * 4];
  __shared__ float sWB[4 * 81 * 8];

  const int tid = threadIdx.x;
  const int b   = blockIdx.z;
  const int h0  = (blockIdx.x >> 2) * 16;
  const int w0  = (blockIdx.x & 3) * 32;

  for (int e = tid; e < 32 * 48; e += 256) {
    int r = e / 48, c = e - r * 48;
    int gh = h0 - 8 + r, gw = w0 - 8 + c;
    float v = 0.0f;
    if (gh >= 0 && gh < 128 && gw >= 0 && gw < 128)
      v = in[(size_t)b * HW + gh * 128 + gw];
    sX[e] = v;
  }
  for (int e = tid; e < 324; e += 256) {
    int co = e & 3, tap = e >> 2;
    sWA[tap * 4 + co] = wA[co * 81 + tap];
  }
  for (int e = tid; e < 2592; e += 256) {
    int co = e & 7;
    int rest = e >> 3;
    int tap = rest % 81, ci = rest / 81;
    sWB[(ci * 81 + tap) * 8 + co] = wB[((size_t)co * 4 + ci) * 81 + tap];
  }
  __syncthreads();

  for (int e = tid; e < 960; e += 256) {
    int r = e / 40, c = e - r * 40;
    int gh = h0 - 4 + r, gw = w0 - 4 + c;
    float a0 = 0.0f, a1 = 0.0f, a2 = 0.0f, a3 = 0.0f;
    if (gh >= 0 && gh < 128 && gw >= 0 && gw < 128) {
      for (int kh = 0; kh < 9; ++kh) {
#pragma unroll
        for (int kw = 0; kw < 9; ++kw) {
          float x = sX[(r + kh) * 48 + (c + kw)];
          const float* wp = &sWA[(kh * 9 + kw) * 4];
          a0 += x * wp[0]; a1 += x * wp[1]; a2 += x * wp[2]; a3 += x * wp[3];
        }
      }
    }
    sT4[0][r * 41 + c] = a0;
    sT4[1][r * 41 + c] = a1;
    sT4[2][r * 41 + c] = a2;
    sT4[3][r * 41 + c] = a3;
  }
  __syncthreads();

  const int c  = tid & 31;
  const int r0 = tid >> 5;
  float acc[2][8];
#pragma unroll
  for (int j = 0; j < 2; ++j)
#pragma unroll
    for (int co = 0; co < 8; ++co) acc[j][co] = 0.0f;

  for (int ci = 0; ci < 4; ++ci) {
    const float* t4c = sT4[ci];
    for (int kh = 0; kh < 9; ++kh) {
#pragma unroll
      for (int kw = 0; kw < 9; ++kw) {
        float x0 = t4c[(r0 + kh) * 41 + c + kw];
        float x1 = t4c[(r0 + 8 + kh) * 41 + c + kw];
        const float* wp = &sWB[(ci * 81 + kh * 9 + kw) * 8];
#pragma unroll
        for (int co = 0; co < 8; ++co) {
          acc[0][co] += x0 * wp[co];
          acc[1][co] += x1 * wp[co];
        }
      }
    }
  }

#pragma unroll
  for (int j = 0; j < 2; ++j) {
    const int h = h0 + r0 + 8 * j;
    const int w = w0 + c;
#pragma unroll
    for (int co = 0; co < 8; ++co) {
      float v = acc[j][co];
      if (OUT == 0)
        outF[(((size_t)b * 128 + h) * 128 + w) * 8 + co] = v;
      else
        outBf[((size_t)b * HW + h * 128 + w) * 8 + co] = f2bf(v);
    }
  }
}

// ---------------------------------------------------------------------------
// fused tail (r8-verified) + per-block <vin, vout> partial dot -> atomicAdd den.
// ---------------------------------------------------------------------------
__global__ __launch_bounds__(256) void fused_tail(
    const u16* __restrict__ t8v, const float* __restrict__ w11,
    const float* __restrict__ w10, const float* __restrict__ vin,
    const float* __restrict__ lam, float* __restrict__ vout,
    float* __restrict__ den)
{
  __shared__ float sX[8][32 * 33];
  __shared__ float sT4[4][24 * 25];
  __shared__ float sW1[8 * 81 * 4];
  __shared__ float sW0[4 * 81];
  __shared__ float sRed[256];

  const int tid = threadIdx.x;
  const int b   = blockIdx.z;
  const int h0  = (blockIdx.x >> 3) * 16;
  const int w0  = (blockIdx.x & 7) * 16;

  for (int e = tid; e < 1024; e += 256) {
    int r = e >> 5, c = e & 31;
    int gh = h0 - 8 + r, gw = w0 - 8 + c;
    float v[8];
    if (gh >= 0 && gh < 128 && gw >= 0 && gw < 128) {
      const u16* s = t8v + ((size_t)b * HW + gh * 128 + gw) * 8;
#pragma unroll
      for (int ci = 0; ci < 8; ++ci) v[ci] = bf2f(s[ci]);
    } else {
#pragma unroll
      for (int ci = 0; ci < 8; ++ci) v[ci] = 0.0f;
    }
#pragma unroll
    for (int ci = 0; ci < 8; ++ci) sX[ci][r * 33 + c] = v[ci];
  }
  for (int e = tid; e < 2592; e += 256) {
    int co = e & 3;
    int rest = e >> 2;
    int tap = rest % 81, ci = rest / 81;
    sW1[(ci * 81 + tap) * 4 + co] = w11[(size_t)(ci * 4 + co) * 81 + (80 - tap)];
  }
  for (int e = tid; e < 324; e += 256) {
    int tap = e % 81, ci = e / 81;
    sW0[ci * 81 + tap] = w10[(size_t)ci * 81 + (80 - tap)];
  }
  __syncthreads();

  for (int e = tid; e < 288; e += 256) {
    int r = e / 12, c2 = (e - r * 12) * 2;
    int gh = h0 - 4 + r;
    int gw0 = w0 - 4 + c2;
    float a0[4] = {0, 0, 0, 0}, a1[4] = {0, 0, 0, 0};
    for (int ci = 0; ci < 8; ++ci) {
      for (int kh = 0; kh < 9; ++kh) {
        const float* xb = &sX[ci][(r + kh) * 33 + c2];
#pragma unroll
        for (int kw = 0; kw < 9; ++kw) {
          float x0 = xb[kw], x1 = xb[kw + 1];
          const float* wp = &sW1[(ci * 81 + kh * 9 + kw) * 4];
#pragma unroll
          for (int co = 0; co < 4; ++co) {
            a0[co] += x0 * wp[co];
            a1[co] += x1 * wp[co];
          }
        }
      }
    }
    bool in0 = (gh >= 0 && gh < 128 && gw0 >= 0 && gw0 < 128);
    bool in1 = (gh >= 0 && gh < 128 && (gw0 + 1) >= 0 && (gw0 + 1) < 128);
#pragma unroll
    for (int co = 0; co < 4; ++co) {
      sT4[co][r * 25 + c2]     = in0 ? a0[co] : 0.0f;
      sT4[co][r * 25 + c2 + 1] = in1 ? a1[co] : 0.0f;
    }
  }
  __syncthreads();

  {
    int r = tid >> 4, c = tid & 15;
    float acc = 0.0f;
    for (int ci = 0; ci < 4; ++ci) {
      for (int kh = 0; kh < 9; ++kh) {
        const float* xb = &sT4[ci][(r + kh) * 25 + c];
        const float* wp = &sW0[ci * 81 + kh * 9];
#pragma unroll
        for (int kw = 0; kw < 9; ++kw) acc += xb[kw] * wp[kw];
      }
    }
    size_t o = (size_t)b * HW + (h0 + r) * 128 + (w0 + c);
    float l = lam[b];
    float vi = vin[o];
    float res = (vi + l * acc) / (1.0f + l);
    vout[o] = res;
    sRed[tid] = vi * res;          // partial <vin, Bp>
  }
  __syncthreads();
  for (int st = 128; st > 0; st >>= 1) {
    if (tid < st) sRed[tid] += sRed[tid + st];
    __syncthreads();
  }
  if (tid == 0) atomicAdd(&den[b], sRed[0]);
}

// ---------------------------------------------------------------------------
// helpers
// ---------------------------------------------------------------------------
__global__ void k_scalars(const float* __restrict__ sigma, const float* __restrict__ c_lam,
                          const float* __restrict__ c_scal, float* __restrict__ lam,
                          float* __restrict__ scal) {
  int tid = threadIdx.x;
  if (tid < BATCH) lam[tid] = spline_eval(sigma[tid], c_lam, 53, -1.0f, 51.0f);
  for (int j = tid; j < BATCH * 128; j += 256) {
    int b = j >> 7, chn = j & 127;
    float s = sigma[b];
    scal[j] = expf(spline_eval(s, c_scal + chn * 14, 14, -1.0f, 51.0f)) / (s + 1e-5f);
  }
}

__global__ void k_binit(const float* __restrict__ y, const float* __restrict__ lam,
                        float* __restrict__ bimg, float* __restrict__ x) {
  int i = blockIdx.x * 256 + threadIdx.x;
  int b = i >> 14;
  bimg[i] = y[i] / (1.0f + lam[b]);
  x[i] = 0.0f;
}

// r = bimg - Bp; p = r; rn[b] = <r,r>; den[b] = 0   (one block per image)
__global__ void k_cg0(const float* __restrict__ bimg, const float* __restrict__ Bp,
                      float* __restrict__ r, float* __restrict__ p,
                      float* __restrict__ rn, float* __restrict__ den) {
  __shared__ float s[256];
  int b = blockIdx.x;
  size_t base = (size_t)b << 14;
  float local = 0.0f;
  for (int i = threadIdx.x; i < HW; i += 256) {
    float v = bimg[base + i] - Bp[base + i];
    r[base + i] = v;
    p[base + i] = v;
    local += v * v;
  }
  s[threadIdx.x] = local;
  __syncthreads();
  for (int st = 128; st > 0; st >>= 1) {
    if (threadIdx.x < st) s[threadIdx.x] += s[threadIdx.x + st];
    __syncthreads();
  }
  if (threadIdx.x == 0) { rn[b] = s[0]; den[b] = 0.0f; }
}

// alpha-update + rn2 reduce + beta + p-update; zeroes den for next iteration.
__global__ void k_cg2(float* __restrict__ x, float* __restrict__ r,
                      float* __restrict__ p, const float* __restrict__ Bp,
                      float* __restrict__ rn, float* __restrict__ den) {
  __shared__ float s[256];
  int b = blockIdx.x;
  size_t base = (size_t)b << 14;
  float rnb = rn[b];
  bool act = rnb > 1e-6f;
  float alpha = act ? rnb / den[b] : 0.0f;
  float local = 0.0f;
  for (int i = threadIdx.x; i < HW; i += 256) {
    float pv = p[base + i];
    x[base + i] += alpha * pv;
    float rr = r[base + i] - alpha * Bp[base + i];
    r[base + i] = rr;
    local += rr * rr;
  }
  s[threadIdx.x] = local;
  __syncthreads();
  for (int st = 128; st > 0; st >>= 1) {
    if (threadIdx.x < st) s[threadIdx.x] += s[threadIdx.x + st];
    __syncthreads();
  }
  float rn2 = s[0];
  float beta = act ? rn2 / rnb : 0.0f;
  if (threadIdx.x == 0) { rn[b] = rn2; den[b] = 0.0f; }
  for (int i = threadIdx.x; i < HW; i += 256)
    p[base + i] = r[base + i] + beta * p[base + i];
}

__global__ void k_copy(const float* __restrict__ x, float* __restrict__ out) {
  int i = blockIdx.x * 256 + threadIdx.x;
  out[i] = x[i];
}

// ---------------------------------------------------------------------------
extern "C" void kernel_launch(void* const* d_in, const int* in_sizes, int n_in_,
                              void* d_out, int out_size, void* d_ws, size_t ws_size,
                              hipStream_t stream) {
  const float* y      = (const float*)d_in[0];
  const float* sigma  = (const float*)d_in[1];
  const float* w1_0   = (const float*)d_in[2];
  const float* w1_1   = (const float*)d_in[3];
  const float* w1_2   = (const float*)d_in[4];
  const float* m1_0   = (const float*)d_in[5];
  const float* m1_1   = (const float*)d_in[6];
  const float* m1_2   = (const float*)d_in[7];
  const float* m2_w   = (const float*)d_in[8];
  const float* m3_w   = (const float*)d_in[9];
  const float* c_sp1  = (const float*)d_in[10];
  const float* c_sp2  = (const float*)d_in[11];
  const float* c_sp3  = (const float*)d_in[12];
  const float* c_lam  = (const float*)d_in[13];
  const float* c_scal = (const float*)d_in[14];
  // n_out = 2, n_in = 6 fixed by setup_inputs

  char* cur = (char*)d_ws;
  auto alloc = [&](size_t bytes) {
    char* p = cur;
    cur += (bytes + 255) & ~(size_t)255;
    return p;
  };

  // weight fragments (~3 MB)
  u16* wA_hi  = (u16*)alloc(86016 * 2);
  u16* wA_lo  = (u16*)alloc(86016 * 2);
  u16* wAm_hi = (u16*)alloc(86016 * 2);
  u16* wAm_lo = (u16*)alloc(86016 * 2);
  u16* wB_hi  = (u16*)alloc(172032 * 2);
  u16* wB_lo  = (u16*)alloc(172032 * 2);
  u16* wC2_hi = (u16*)alloc(196608 * 2);
  u16* wC2_lo = (u16*)alloc(196608 * 2);
  u16* wC3_hi = (u16*)alloc(196608 * 2);
  u16* wC3_lo = (u16*)alloc(196608 * 2);

  // region1 (67.1 MB): mask phase = P1f fp32 NHWC128; CG = big2c bf16 slice-major
  char* region1 = alloc((size_t)16777216 * 4);
  float* P1f   = (float*)region1;
  u16*   big2c = (u16*)region1;
  // mask_c bf16 slice-major [8][16][HW][8] (33.5 MB)
  u16* mask_c = (u16*)alloc((size_t)16777216 * 2);
  // region2 (33.6 MB): mask phase = P2s fp32 NHWC128 x 4 batches; CG = t8v bf16
  char* region2 = alloc((size_t)4 * 128 * 128 * 128 * 4);
  float* P2s = (float*)region2;
  u16*   t8v = (u16*)region2;
  // region3 (4.2 MB): mask phase = t8f fp32 NHWC8; CG = t8c bf16 slice-major
  char* region3 = alloc((size_t)1048576 * 4);
  float* t8f = (float*)region3;
  u16*   t8c = (u16*)region3;

  float* bimg = (float*)alloc(131072 * 4);
  float* xbuf = (float*)alloc(131072 * 4);
  float* rbuf = (float*)alloc(131072 * 4);
  float* pbuf = (float*)alloc(131072 * 4);
  float* Bp   = (float*)alloc(131072 * 4);
  float* lam  = (float*)alloc(8 * 4);
  float* scal = (float*)alloc(1024 * 4);
  float* rn   = (float*)alloc(8 * 4);
  float* den  = (float*)alloc(8 * 4);
  // total ~144 MB (r8's passing layout)

  const dim3 blk(256);

  k_prepw<9, 8, 128, 8, 1, 81, 21, false><<<dim3(42), blk, 0, stream>>>(w1_2, wA_hi, wA_lo);
  k_prepw<9, 8, 128, 8, 1, 81, 21, false><<<dim3(42), blk, 0, stream>>>(m1_2, wAm_hi, wAm_lo);
  k_prepw<9, 8, 8, 1, 16, 81, 21, true><<<dim3(84), blk, 0, stream>>>(w1_2, wB_hi, wB_lo);
  k_prepw<3, 128, 128, 8, 16, 9, 3, false><<<dim3(96), blk, 0, stream>>>(m2_w, wC2_hi, wC2_lo);
  k_prepw<3, 128, 128, 8, 16, 9, 3, false><<<dim3(96), blk, 0, stream>>>(m3_w, wC3_hi, wC3_lo);

  k_scalars<<<dim3(1), blk, 0, stream>>>(sigma, c_lam, c_scal, lam, scal);
  k_binit<<<dim3(512), blk, 0, stream>>>(y, lam, bimg, xbuf);

  auto BtB = [&](const float* vin, float* vout) {
    fused_fwd<1><<<dim3(32, 1, 8), blk, 0, stream>>>(vin, w1_0, w1_1, nullptr, t8c);
    bconv<9, 1, 81, 21, 4, 8, 3><<<dim3(64, 8, 2), blk, 0, stream>>>(
        t8c, wA_hi, big2c, mask_c);
    bconv<9, 16, 81, 21, 1, 1, 4><<<dim3(64, 8, 1), blk, 0, stream>>>(
        big2c, wB_hi, t8v, nullptr);
    fused_tail<<<dim3(64, 1, 8), blk, 0, stream>>>(t8v, w1_1, w1_0, vin, lam, vout, den);
  };

  for (int outer = 0; outer < 2; ++outer) {
    // ---- mask = cal_mask(c_k = xbuf); 3-term fp32 path, NT=4 ----
    fused_fwd<0><<<dim3(32, 1, 8), blk, 0, stream>>>(xbuf, m1_0, m1_1, t8f, nullptr);
    mconv<9, 8, 1, 81, 21, 16, 4, 4, 8, 1><<<dim3(64, 8, 2), blk, 0, stream>>>(
        t8f, wAm_hi, wAm_lo, P1f, nullptr, c_sp1, nullptr, 0, 0);
    for (int bc = 0; bc < 2; ++bc) {
      mconv<3, 128, 16, 9, 3, 16, 4, 4, 8, 1><<<dim3(64, 4, 2), blk, 0, stream>>>(
          P1f, wC2_hi, wC2_lo, P2s, nullptr, c_sp2, nullptr, bc * 4, 0);
      mconv<3, 128, 16, 9, 3, 16, 4, 4, 8, 2><<<dim3(64, 4, 2), blk, 0, stream>>>(
          P2s, wC3_hi, wC3_lo, nullptr, mask_c, c_sp3, scal, 0, bc * 4);
    }

    // ---- CG ----
    BtB(xbuf, Bp);
    k_cg0<<<dim3(8), blk, 0, stream>>>(bimg, Bp, rbuf, pbuf, rn, den);

    for (int it = 0; it < 6; ++it) {
      BtB(pbuf, Bp);
      k_cg2<<<dim3(8), blk, 0, stream>>>(xbuf, rbuf, pbuf, Bp, rn, den);
    }
  }

  k_copy<<<dim3(512), blk, 0, stream>>>(xbuf, (float*)d_out);
}

// Round 10
// 3655.738 us; speedup vs baseline: 1.0301x; 1.0301x over previous
//
#include <hip/hip_runtime.h>

#define HW 16384
#define BATCH 8

typedef unsigned short u16;
typedef __attribute__((ext_vector_type(8))) short bfrag;   // 8 bf16 in 4 VGPRs
typedef __attribute__((ext_vector_type(4))) float ffrag;   // MFMA accumulator
typedef __attribute__((ext_vector_type(4))) float f4v;

// ---------------------------------------------------------------------------
__device__ __forceinline__ u16 f2bf(float f) {
  unsigned int u = __float_as_uint(f);
  u += 0x7FFFu + ((u >> 16) & 1u);
  return (u16)(u >> 16);
}
__device__ __forceinline__ float bf2f(u16 h) {
  return __uint_as_float(((unsigned int)h) << 16);
}
__device__ __forceinline__ ffrag mfma16(bfrag a, bfrag b, ffrag c) {
  return __builtin_amdgcn_mfma_f32_16x16x32_bf16(a, b, c, 0, 0, 0);
}

__device__ __forceinline__ float spline_eval(float x, const float* __restrict__ c,
                                             int K, float xmin, float xmax) {
  float step = (xmax - xmin) / (float)(K - 1);
  float t = (x - xmin) / step;
  float fidx = floorf(t);
  fidx = fminf(fmaxf(fidx, 0.0f), (float)(K - 2));
  int idx = (int)fidx;
  float frac = t - fidx;
  return c[idx] * (1.0f - frac) + c[idx + 1] * frac;
}
__device__ __forceinline__ float spline31(float x, const float* __restrict__ c) {
  float t = x * 10.0f;
  float fi = floorf(t);
  fi = fminf(fmaxf(fi, 0.0f), 29.0f);
  int i = (int)fi;
  float fr = t - fi;
  return c[i] * (1.0f - fr) + c[i + 1] * fr;
}

// ---------------------------------------------------------------------------
// Weight prep: OIHW fp32 -> MFMA B-fragment order, bf16 hi/lo planes. (r4-r9)
// ---------------------------------------------------------------------------
template<int KS, int CIW, int CO, int NTT, int NSLICE, int TAPS, int CHUNKS, bool TR>
__global__ void k_prepw(const float* __restrict__ W, u16* __restrict__ hi,
                        u16* __restrict__ lo) {
  int gid = blockIdx.x * 256 + threadIdx.x;
  const int total = NSLICE * CHUNKS * NTT * 64;
  if (gid >= total) return;
  int L = gid & 63;
  int rest = gid >> 6;
  int ntg = rest % NTT; rest /= NTT;
  int ch = rest % CHUNKS;
  int sl = rest / CHUNKS;
  int q = L >> 4, n = L & 15;
  int tap = ch * 4 + q;
  int co = ntg * 16 + n;
  int dh = tap / KS, dw = tap - dh * KS;
  for (int j = 0; j < 8; ++j) {
    int ci = sl * 8 + j;
    float v = 0.0f;
    if (tap < TAPS && co < CO) {
      if (TR)
        v = W[(((size_t)ci * CO + co) * KS + (KS - 1 - dh)) * KS + (KS - 1 - dw)];
      else
        v = W[(((size_t)co * CIW + ci) * KS + dh) * KS + dw];
    }
    u16 h = f2bf(v);
    hi[(size_t)gid * 8 + j] = h;
    lo[(size_t)gid * 8 + j] = f2bf(v - bf2f(h));
  }
}

// ---------------------------------------------------------------------------
// bconv (r6-verified exact): LDS-staged 1-term bf16 MFMA conv, CG path.
// EPI 0: outF NCHW fp32, co<8 | EPI 3: v*m^2 -> slice-major bf16
// ---------------------------------------------------------------------------
template<int KS, int SLICES, int TAPS, int CHUNKS, int NT, int NTT, int EPI>
__global__ __launch_bounds__(256) void bconv(
    const u16* __restrict__ in, const u16* __restrict__ wHi,
    float* __restrict__ outF, u16* __restrict__ outBf,
    const u16* __restrict__ mskc)
{
  constexpr int P  = KS / 2;
  constexpr int IW = 16 + 2 * P;
  constexpr int IH = 16 + 2 * P;

  __shared__ __align__(16) u16 sA[IH * IW * 8];

  const int tid = threadIdx.x;
  const int wv  = tid >> 6;
  const int L   = tid & 63;
  const int q   = L >> 4;
  const int n16 = L & 15;

  const int tx = blockIdx.x & 7, ty = blockIdx.x >> 3;
  const int w0 = tx * 16, h0 = ty * 16;
  const int bb = blockIdx.y;
  const int bz = blockIdx.z;

  ffrag acc[4][NT];
#pragma unroll
  for (int i = 0; i < 4; ++i)
#pragma unroll
    for (int t = 0; t < NT; ++t) acc[i][t] = (ffrag)0.0f;

  for (int slc = 0; slc < SLICES; ++slc) {
    __syncthreads();
    for (int e = tid; e < IH * IW; e += 256) {
      int ih = e / IW, iw = e - ih * IW;
      int gh = h0 + ih - P, gw = w0 + iw - P;
      f4v v = (f4v)0.0f;
      if (gh >= 0 && gh < 128 && gw >= 0 && gw < 128)
        v = *(const f4v*)(in + (((size_t)(bb * SLICES + slc) * HW) + gh * 128 + gw) * 8);
      *(f4v*)(sA + (size_t)e * 8) = v;
    }
    __syncthreads();

    const u16* wS = wHi + (size_t)slc * CHUNKS * NTT * 512;
    for (int ch = 0; ch < CHUNKS; ++ch) {
      int tap = ch * 4 + q;
      int dh = 0, dw = 0;
      if (tap < TAPS) { dh = tap / KS; dw = tap - dh * KS; }
      int toff = dh * IW + dw;
      bfrag A[4];
#pragma unroll
      for (int i = 0; i < 4; ++i)
        A[i] = *(const bfrag*)(sA + ((wv * 4 + i) * IW + n16 + toff) * 8);
#pragma unroll
      for (int t = 0; t < NT; ++t) {
        bfrag B = *(const bfrag*)(wS + ((size_t)ch * NTT + bz * NT + t) * 512 + L * 8);
#pragma unroll
        for (int i = 0; i < 4; ++i) acc[i][t] = mfma16(A[i], B, acc[i][t]);
      }
    }
  }

#pragma unroll
  for (int i = 0; i < 4; ++i) {
    const int h = h0 + wv * 4 + i;
#pragma unroll
    for (int t = 0; t < NT; ++t) {
      const int co = bz * (NT * 16) + t * 16 + n16;
#pragma unroll
      for (int r = 0; r < 4; ++r) {
        const int w = w0 + q * 4 + r;
        float v = acc[i][t][r];
        if (EPI == 0) {
          if (n16 < 8)
            outF[(((size_t)bb * 8 + n16) * 128 + h) * 128 + w] = v;
        } else if (EPI == 3) {
          size_t o = (((size_t)(bb * 16 + (co >> 3)) * HW) + h * 128 + w) * 8 + (co & 7);
          float m = bf2f(mskc[o]);
          outBf[o] = f2bf(v * m * m);
        }
      }
    }
  }
}

// ---------------------------------------------------------------------------
// mconv: 3-term split MFMA conv; activations PRE-SPLIT in memory as hi/lo
// bf16 slice-major planes [b][s][HW][8] (bit-identical to the r8 path which
// split fp32 in-kernel). Staging = pure 16B copies.
// EPI 1: spline31(|v|) -> hi/lo slice-major planes
// EPI 2: clip(spline31(sl*|v|),.01,1) -> mask_c single bf16 slice-major
// ---------------------------------------------------------------------------
template<int KS, int CIN, int NSLICE, int TAPS, int CHUNKS,
         int TH, int MTW, int NT, int NTT, int EPI>
__global__ __launch_bounds__(256) void mconv(
    const u16* __restrict__ inHi, const u16* __restrict__ inLo,
    const u16* __restrict__ wHi, const u16* __restrict__ wLo,
    u16* __restrict__ outHi, u16* __restrict__ outLo,
    const float* __restrict__ sp, const float* __restrict__ sl,
    int binOfs, int boutOfs)
{
  constexpr int P  = KS / 2;
  constexpr int IW = 16 + 2 * P;
  constexpr int IH = TH + 2 * P;

  __shared__ __align__(16) u16 sHi[IH * IW * 8];
  __shared__ __align__(16) u16 sLo[IH * IW * 8];

  const int tid = threadIdx.x;
  const int wv  = tid >> 6;
  const int L   = tid & 63;
  const int q   = L >> 4;
  const int n16 = L & 15;

  const int tx = blockIdx.x & 7;
  const int ty = blockIdx.x >> 3;
  const int w0 = tx * 16, h0 = ty * TH;
  const int bin  = (int)blockIdx.y + binOfs;
  const int bout = (int)blockIdx.y + boutOfs;
  const int bz = blockIdx.z;

  ffrag acc[MTW][NT];
#pragma unroll
  for (int i = 0; i < MTW; ++i)
#pragma unroll
    for (int t = 0; t < NT; ++t) acc[i][t] = (ffrag)0.0f;

  for (int slc = 0; slc < NSLICE; ++slc) {
    __syncthreads();
    for (int e = tid; e < IH * IW; e += 256) {
      int ih = e / IW, iw = e - ih * IW;
      int gh = h0 + ih - P, gw = w0 + iw - P;
      f4v vh = (f4v)0.0f, vl = (f4v)0.0f;
      if (gh >= 0 && gh < 128 && gw >= 0 && gw < 128) {
        size_t g = (((size_t)(bin * (CIN / 8) + slc) * HW) + gh * 128 + gw) * 8;
        vh = *(const f4v*)(inHi + g);
        vl = *(const f4v*)(inLo + g);
      }
      *(f4v*)(sHi + (size_t)e * 8) = vh;
      *(f4v*)(sLo + (size_t)e * 8) = vl;
    }
    __syncthreads();

    const u16* wHs = wHi + (size_t)slc * CHUNKS * NTT * 512;
    const u16* wLs = wLo + (size_t)slc * CHUNKS * NTT * 512;
    for (int ch = 0; ch < CHUNKS; ++ch) {
      int tap = ch * 4 + q;
      int dh = tap / KS;
      int dw = tap - dh * KS;
      int toff = (tap < TAPS) ? (dh * IW + dw) : 0;
      bfrag Ah[MTW], Al[MTW];
#pragma unroll
      for (int i = 0; i < MTW; ++i) {
        int a8 = ((wv * MTW + i) * IW + n16 + toff) * 8;
        Ah[i] = *(const bfrag*)(sHi + a8);
        Al[i] = *(const bfrag*)(sLo + a8);
      }
#pragma unroll
      for (int t = 0; t < NT; ++t) {
        size_t off = ((size_t)ch * NTT + bz * NT + t) * 512 + L * 8;
        bfrag Bh = *(const bfrag*)(wHs + off);
        bfrag Bl = *(const bfrag*)(wLs + off);
#pragma unroll
        for (int i = 0; i < MTW; ++i) {
          acc[i][t] = mfma16(Ah[i], Bh, acc[i][t]);
          acc[i][t] = mfma16(Ah[i], Bl, acc[i][t]);
          acc[i][t] = mfma16(Al[i], Bh, acc[i][t]);
        }
      }
    }
  }

#pragma unroll
  for (int i = 0; i < MTW; ++i) {
    const int h = h0 + wv * MTW + i;
#pragma unroll
    for (int t = 0; t < NT; ++t) {
      const int co = bz * (NT * 16) + t * 16 + n16;
#pragma unroll
      for (int r = 0; r < 4; ++r) {
        const int w = w0 + q * 4 + r;
        float v = acc[i][t][r];
        size_t o = (((size_t)(bout * 16 + (co >> 3)) * HW) + h * 128 + w) * 8 + (co & 7);
        if (EPI == 1) {
          float x = spline31(fabsf(v), sp);
          u16 hb = f2bf(x);
          outHi[o] = hb;
          outLo[o] = f2bf(x - bf2f(hb));
        } else if (EPI == 2) {
          float s = sl[bout * 128 + co];
          float x = spline31(s * fabsf(v), sp);
          x = fminf(fmaxf(x, 0.01f), 1.0f);
          outHi[o] = f2bf(x);   // mask_c single plane
        }
      }
    }
  }
}

// ---------------------------------------------------------------------------
// fused forward 1->4->8 (r5-r9 verified core).
// OUT 0: hi/lo bf16 slice-major 8ch | OUT 1: single bf16 slice-major 8ch
// ---------------------------------------------------------------------------
template<int OUT>
__global__ __launch_bounds__(256) void fused_fwd(
    const float* __restrict__ in, const float* __restrict__ wA,
    const float* __restrict__ wB, u16* __restrict__ oHi,
    u16* __restrict__ oLo)
{
  __shared__ float sX[32 * 48];
  __shared__ float sT4[4][24 * 41];
  __shared__ float sWA[81 * 4];
  __shared__ float sWB[4 * 81 * 8];

  const int tid = threadIdx.x;
  const int b   = blockIdx.z;
  const int h0  = (blockIdx.x >> 2) * 16;
  const int w0  = (blockIdx.x & 3) * 32;

  for (int e = tid; e < 32 * 48; e += 256) {
    int r = e / 48, c = e - r * 48;
    int gh = h0 - 8 + r, gw = w0 - 8 + c;
    float v = 0.0f;
    if (gh >= 0 && gh < 128 && gw >= 0 && gw < 128)
      v = in[(size_t)b * HW + gh * 128 + gw];
    sX[e] = v;
  }
  for (int e = tid; e < 324; e += 256) {
    int co = e & 3, tap = e >> 2;
    sWA[tap * 4 + co] = wA[co * 81 + tap];
  }
  for (int e = tid; e < 2592; e += 256) {
    int co = e & 7;
    int rest = e >> 3;
    int tap = rest % 81, ci = rest / 81;
    sWB[(ci * 81 + tap) * 8 + co] = wB[((size_t)co * 4 + ci) * 81 + tap];
  }
  __syncthreads();

  for (int e = tid; e < 960; e += 256) {
    int r = e / 40, c = e - r * 40;
    int gh = h0 - 4 + r, gw = w0 - 4 + c;
    float a0 = 0.0f, a1 = 0.0f, a2 = 0.0f, a3 = 0.0f;
    if (gh >= 0 && gh < 128 && gw >= 0 && gw < 128) {
      for (int kh = 0; kh < 9; ++kh) {
#pragma unroll
        for (int kw = 0; kw < 9; ++kw) {
          float x = sX[(r + kh) * 48 + (c + kw)];
          const float* wp = &sWA[(kh * 9 + kw) * 4];
          a0 += x * wp[0]; a1 += x * wp[1]; a2 += x * wp[2]; a3 += x * wp[3];
        }
      }
    }
    sT4[0][r * 41 + c] = a0;
    sT4[1][r * 41 + c] = a1;
    sT4[2][r * 41 + c] = a2;
    sT4[3][r * 41 + c] = a3;
  }
  __syncthreads();

  const int c  = tid & 31;
  const int r0 = tid >> 5;
  float acc[2][8];
#pragma unroll
  for (int j = 0; j < 2; ++j)
#pragma unroll
    for (int co = 0; co < 8; ++co) acc[j][co] = 0.0f;

  for (int ci = 0; ci < 4; ++ci) {
    const float* t4c = sT4[ci];
    for (int kh = 0; kh < 9; ++kh) {
#pragma unroll
      for (int kw = 0; kw < 9; ++kw) {
        float x0 = t4c[(r0 + kh) * 41 + c + kw];
        float x1 = t4c[(r0 + 8 + kh) * 41 + c + kw];
        const float* wp = &sWB[(ci * 81 + kh * 9 + kw) * 8];
#pragma unroll
        for (int co = 0; co < 8; ++co) {
          acc[0][co] += x0 * wp[co];
          acc[1][co] += x1 * wp[co];
        }
      }
    }
  }

#pragma unroll
  for (int j = 0; j < 2; ++j) {
    const int h = h0 + r0 + 8 * j;
    const int w = w0 + c;
#pragma unroll
    for (int co = 0; co < 8; ++co) {
      float v = acc[j][co];
      size_t o = ((size_t)b * HW + h * 128 + w) * 8 + co;
      if (OUT == 0) {
        u16 hb = f2bf(v);
        oHi[o] = hb;
        oLo[o] = f2bf(v - bf2f(hb));
      } else {
        oHi[o] = f2bf(v);
      }
    }
  }
}

// ---------------------------------------------------------------------------
// fp32 direct conv, transposed small shapes (r2/r6-verified core).
// EPI 0: NCHW fp32 | EPI 5: out = (aux + lam*v)/(1+lam), CO==1
// ---------------------------------------------------------------------------
template<int KS, int CI, int CO, int CIC, int COT, int TH, int EPI, bool TR>
__global__ __launch_bounds__(256) void conv_k(
    const float* __restrict__ in, const float* __restrict__ wt,
    float* __restrict__ out, const float* __restrict__ aux,
    const float* __restrict__ sl)
{
  constexpr int P  = KS / 2;
  constexpr int TW = 32;
  constexpr int IH = TH + 2 * P;
  constexpr int IW = TW + 2 * P;
  constexpr int RPT = TH / 8;
  constexpr int NCH = CI / CIC;
  static_assert(CIC * NCH == CI, "channel split mismatch");

  __shared__ float sIn[CIC * IH * IW];
  __shared__ float sW[CIC * KS * KS * COT];

  const int tid = threadIdx.x;
  const int nTW = 128 / TW;
  const int th0 = (blockIdx.x / nTW) * TH;
  const int tw0 = (blockIdx.x % nTW) * TW;
  const int b   = blockIdx.z;

  float acc[RPT][COT];
#pragma unroll
  for (int j = 0; j < RPT; ++j)
#pragma unroll
    for (int co = 0; co < COT; ++co) acc[j][co] = 0.0f;

  const int c  = tid & 31;
  const int r0 = tid >> 5;

  for (int ch = 0; ch < NCH; ++ch) {
    const int ci0 = ch * CIC;
    __syncthreads();
    for (int e = tid; e < CIC * IH * IW; e += 256) {
      int ci  = e / (IH * IW);
      int rem = e - ci * (IH * IW);
      int ih  = rem / IW;
      int iw  = rem - ih * IW;
      int gh = th0 + ih - P, gw = tw0 + iw - P;
      float v = 0.0f;
      if (gh >= 0 && gh < 128 && gw >= 0 && gw < 128)
        v = in[((size_t)(b * CI + ci0 + ci) * 128 + gh) * 128 + gw];
      sIn[e] = v;
    }
    for (int e = tid; e < CIC * KS * KS * COT; e += 256) {
      int co = e & (COT - 1);
      int k  = e / COT;
      int ci = k / (KS * KS);
      int kk = k - ci * (KS * KS);
      int kh = kk / KS, kw = kk - kh * KS;
      float wv;
      if (!TR)
        wv = wt[(((size_t)co * CI + ci0 + ci) * KS + kh) * KS + kw];
      else
        wv = wt[(((size_t)(ci0 + ci) * CO + co) * KS + (KS - 1 - kh)) * KS + (KS - 1 - kw)];
      sW[e] = wv;
    }
    __syncthreads();

    for (int ci = 0; ci < CIC; ++ci) {
      for (int kh = 0; kh < KS; ++kh) {
        const float* inb = &sIn[(ci * IH + r0 + kh) * IW + c];
        const float* wb  = &sW[(ci * KS + kh) * KS * COT];
#pragma unroll
        for (int kw = 0; kw < KS; ++kw) {
          float xv[RPT];
#pragma unroll
          for (int j = 0; j < RPT; ++j) xv[j] = inb[8 * j * IW + kw];
#pragma unroll
          for (int co = 0; co < COT; ++co) {
            float wv = wb[kw * COT + co];
#pragma unroll
            for (int j = 0; j < RPT; ++j) acc[j][co] += xv[j] * wv;
          }
        }
      }
    }
  }

#pragma unroll
  for (int j = 0; j < RPT; ++j) {
    const int h = th0 + r0 + 8 * j;
    const int w = tw0 + c;
#pragma unroll
    for (int co = 0; co < COT; ++co) {
      float v = acc[j][co];
      if (EPI == 5) {
        size_t o = ((size_t)b * 128 + h) * 128 + w;
        float l = sl[b];
        out[o] = (aux[o] + l * v) / (1.0f + l);
      } else {
        out[((size_t)(b * CO + co) * 128 + h) * 128 + w] = v;
      }
    }
  }
}

// ---------------------------------------------------------------------------
// helpers
// ---------------------------------------------------------------------------
__global__ void k_scalars(const float* __restrict__ sigma, const float* __restrict__ c_lam,
                          const float* __restrict__ c_scal, float* __restrict__ lam,
                          float* __restrict__ scal) {
  int tid = threadIdx.x;
  if (tid < BATCH) lam[tid] = spline_eval(sigma[tid], c_lam, 53, -1.0f, 51.0f);
  for (int j = tid; j < BATCH * 128; j += 256) {
    int b = j >> 7, chn = j & 127;
    float s = sigma[b];
    scal[j] = expf(spline_eval(s, c_scal + chn * 14, 14, -1.0f, 51.0f)) / (s + 1e-5f);
  }
}

__global__ void k_binit(const float* __restrict__ y, const float* __restrict__ lam,
                        float* __restrict__ bimg, float* __restrict__ x) {
  int i = blockIdx.x * 256 + threadIdx.x;
  int b = i >> 14;
  bimg[i] = y[i] / (1.0f + lam[b]);
  x[i] = 0.0f;
}

__global__ void k_dot(const float* __restrict__ a, const float* __restrict__ bv,
                      float* __restrict__ out) {
  __shared__ float s[256];
  int b = blockIdx.x;
  float sum = 0.0f;
  for (int i = threadIdx.x; i < HW; i += 256) sum += a[b * HW + i] * bv[b * HW + i];
  s[threadIdx.x] = sum;
  __syncthreads();
  for (int st = 128; st > 0; st >>= 1) {
    if (threadIdx.x < st) s[threadIdx.x] += s[threadIdx.x + st];
    __syncthreads();
  }
  if (threadIdx.x == 0) out[b] = s[0];
}

// r = bimg - Bp; p = r; rn[b] = <r,r>   (one block per image; r8-verified)
__global__ void k_cg0(const float* __restrict__ bimg, const float* __restrict__ Bp,
                      float* __restrict__ r, float* __restrict__ p,
                      float* __restrict__ rn) {
  __shared__ float s[256];
  int b = blockIdx.x;
  size_t base = (size_t)b << 14;
  float local = 0.0f;
  for (int i = threadIdx.x; i < HW; i += 256) {
    float v = bimg[base + i] - Bp[base + i];
    r[base + i] = v;
    p[base + i] = v;
    local += v * v;
  }
  s[threadIdx.x] = local;
  __syncthreads();
  for (int st = 128; st > 0; st >>= 1) {
    if (threadIdx.x < st) s[threadIdx.x] += s[threadIdx.x + st];
    __syncthreads();
  }
  if (threadIdx.x == 0) rn[b] = s[0];
}

// alpha-update + rn2 reduce + beta + p-update (r8-verified); optional x->xout.
__global__ void k_cg2(float* __restrict__ x, float* __restrict__ r,
                      float* __restrict__ p, const float* __restrict__ Bp,
                      float* __restrict__ rn, const float* __restrict__ den,
                      float* __restrict__ xout) {
  __shared__ float s[256];
  int b = blockIdx.x;
  size_t base = (size_t)b << 14;
  float rnb = rn[b];
  bool act = rnb > 1e-6f;
  float alpha = act ? rnb / den[b] : 0.0f;
  float local = 0.0f;
  for (int i = threadIdx.x; i < HW; i += 256) {
    float pv = p[base + i];
    float xv = x[base + i] + alpha * pv;
    x[base + i] = xv;
    if (xout) xout[base + i] = xv;
    float rr = r[base + i] - alpha * Bp[base + i];
    r[base + i] = rr;
    local += rr * rr;
  }
  s[threadIdx.x] = local;
  __syncthreads();
  for (int st = 128; st > 0; st >>= 1) {
    if (threadIdx.x < st) s[threadIdx.x] += s[threadIdx.x + st];
    __syncthreads();
  }
  float rn2 = s[0];
  float beta = act ? rn2 / rnb : 0.0f;
  if (threadIdx.x == 0) rn[b] = rn2;
  for (int i = threadIdx.x; i < HW; i += 256)
    p[base + i] = r[base + i] + beta * p[base + i];
}

// ---------------------------------------------------------------------------
extern "C" void kernel_launch(void* const* d_in, const int* in_sizes, int n_in_,
                              void* d_out, int out_size, void* d_ws, size_t ws_size,
                              hipStream_t stream) {
  const float* y      = (const float*)d_in[0];
  const float* sigma  = (const float*)d_in[1];
  const float* w1_0   = (const float*)d_in[2];
  const float* w1_1   = (const float*)d_in[3];
  const float* w1_2   = (const float*)d_in[4];
  const float* m1_0   = (const float*)d_in[5];
  const float* m1_1   = (const float*)d_in[6];
  const float* m1_2   = (const float*)d_in[7];
  const float* m2_w   = (const float*)d_in[8];
  const float* m3_w   = (const float*)d_in[9];
  const float* c_sp1  = (const float*)d_in[10];
  const float* c_sp2  = (const float*)d_in[11];
  const float* c_sp3  = (const float*)d_in[12];
  const float* c_lam  = (const float*)d_in[13];
  const float* c_scal = (const float*)d_in[14];
  // n_out = 2, n_in = 6 fixed by setup_inputs

  char* cur = (char*)d_ws;
  auto alloc = [&](size_t bytes) {
    char* p = cur;
    cur += (bytes + 255) & ~(size_t)255;
    return p;
  };

  // weight fragments (~3 MB)
  u16* wA_hi  = (u16*)alloc(86016 * 2);
  u16* wA_lo  = (u16*)alloc(86016 * 2);
  u16* wAm_hi = (u16*)alloc(86016 * 2);
  u16* wAm_lo = (u16*)alloc(86016 * 2);
  u16* wB_hi  = (u16*)alloc(172032 * 2);
  u16* wB_lo  = (u16*)alloc(172032 * 2);
  u16* wC2_hi = (u16*)alloc(196608 * 2);
  u16* wC2_lo = (u16*)alloc(196608 * 2);
  u16* wC3_hi = (u16*)alloc(196608 * 2);
  u16* wC3_lo = (u16*)alloc(196608 * 2);

  // region1 (67.1 MB): mask phase = P1 hi+lo planes; CG = big2c (33.5) alias
  char* region1 = alloc((size_t)16777216 * 2 * 2);
  u16* P1hi  = (u16*)region1;
  u16* P1lo  = (u16*)(region1 + (size_t)16777216 * 2);
  u16* big2c = (u16*)region1;
  // mask_c single bf16 slice-major (33.5 MB)
  u16* mask_c = (u16*)alloc((size_t)16777216 * 2);
  // region2 (33.6 MB): mask = P2 hi+lo (4-batch each); CG = t8n fp32 + t4 fp32
  char* region2 = alloc((size_t)8388608 * 2 * 2);
  u16* P2hi = (u16*)region2;
  u16* P2lo = (u16*)(region2 + (size_t)8388608 * 2);
  float* t8n = (float*)region2;                       // 4.2 MB NCHW8 fp32
  float* t4  = (float*)(region2 + (size_t)4194304 * 4);  // 2.1 MB NCHW4 fp32
  // region3 (4.2 MB): mask = t8 hi+lo; CG = t8c single bf16
  char* region3 = alloc((size_t)1048576 * 2 * 2);
  u16* t8hi = (u16*)region3;
  u16* t8lo = (u16*)(region3 + (size_t)1048576 * 2);
  u16* t8c  = (u16*)region3;

  float* bimg = (float*)alloc(131072 * 4);
  float* xbuf = (float*)alloc(131072 * 4);
  float* rbuf = (float*)alloc(131072 * 4);
  float* pbuf = (float*)alloc(131072 * 4);
  float* Bp   = (float*)alloc(131072 * 4);
  float* lam  = (float*)alloc(8 * 4);
  float* scal = (float*)alloc(1024 * 4);
  float* rn   = (float*)alloc(8 * 4);
  float* den  = (float*)alloc(8 * 4);
  // total ~144 MB (r8's passing layout)

  const dim3 blk(256);

  k_prepw<9, 8, 128, 8, 1, 81, 21, false><<<dim3(42), blk, 0, stream>>>(w1_2, wA_hi, wA_lo);
  k_prepw<9, 8, 128, 8, 1, 81, 21, false><<<dim3(42), blk, 0, stream>>>(m1_2, wAm_hi, wAm_lo);
  k_prepw<9, 8, 8, 1, 16, 81, 21, true><<<dim3(84), blk, 0, stream>>>(w1_2, wB_hi, wB_lo);
  k_prepw<3, 128, 128, 8, 16, 9, 3, false><<<dim3(96), blk, 0, stream>>>(m2_w, wC2_hi, wC2_lo);
  k_prepw<3, 128, 128, 8, 16, 9, 3, false><<<dim3(96), blk, 0, stream>>>(m3_w, wC3_hi, wC3_lo);

  k_scalars<<<dim3(1), blk, 0, stream>>>(sigma, c_lam, c_scal, lam, scal);
  k_binit<<<dim3(512), blk, 0, stream>>>(y, lam, bimg, xbuf);

  // CG path: r6-champion configuration (NT=2 bconvA, conv_k tail)
  auto BtB = [&](const float* vin, float* vout) {
    fused_fwd<1><<<dim3(32, 1, 8), blk, 0, stream>>>(vin, w1_0, w1_1, t8c, nullptr);
    bconv<9, 1, 81, 21, 2, 8, 3><<<dim3(64, 8, 4), blk, 0, stream>>>(
        t8c, wA_hi, nullptr, big2c, mask_c);
    bconv<9, 16, 81, 21, 1, 1, 0><<<dim3(64, 8, 1), blk, 0, stream>>>(
        big2c, wB_hi, t8n, nullptr, nullptr);
    conv_k<9, 8, 4, 2, 4, 16, 0, true><<<dim3(32, 1, 8), blk, 0, stream>>>(
        t8n, w1_1, t4, nullptr, nullptr);
    conv_k<9, 4, 1, 1, 1, 16, 5, true><<<dim3(32, 1, 8), blk, 0, stream>>>(
        t4, w1_0, vout, vin, lam);
  };

  for (int outer = 0; outer < 2; ++outer) {
    // ---- mask path: 3-term split MFMA with pre-split hi/lo activations ----
    fused_fwd<0><<<dim3(32, 1, 8), blk, 0, stream>>>(xbuf, m1_0, m1_1, t8hi, t8lo);
    mconv<9, 8, 1, 81, 21, 16, 4, 2, 8, 1><<<dim3(64, 8, 4), blk, 0, stream>>>(
        t8hi, t8lo, wAm_hi, wAm_lo, P1hi, P1lo, c_sp1, nullptr, 0, 0);
    for (int bc = 0; bc < 2; ++bc) {
      mconv<3, 128, 16, 9, 3, 16, 4, 2, 8, 1><<<dim3(64, 4, 4), blk, 0, stream>>>(
          P1hi, P1lo, wC2_hi, wC2_lo, P2hi, P2lo, c_sp2, nullptr, bc * 4, 0);
      mconv<3, 128, 16, 9, 3, 16, 4, 2, 8, 2><<<dim3(64, 4, 4), blk, 0, stream>>>(
          P2hi, P2lo, wC3_hi, wC3_lo, mask_c, nullptr, c_sp3, scal, 0, bc * 4);
    }

    // ---- CG ----
    BtB(xbuf, Bp);
    k_cg0<<<dim3(8), blk, 0, stream>>>(bimg, Bp, rbuf, pbuf, rn);

    for (int it = 0; it < 6; ++it) {
      BtB(pbuf, Bp);
      k_dot<<<dim3(8), blk, 0, stream>>>(pbuf, Bp, den);
      float* xout = (outer == 1 && it == 5) ? (float*)d_out : nullptr;
      k_cg2<<<dim3(8), blk, 0, stream>>>(xbuf, rbuf, pbuf, Bp, rn, den, xout);
    }
  }
}

// Round 11
// 3057.141 us; speedup vs baseline: 1.2318x; 1.1958x over previous
//
#include <hip/hip_runtime.h>

#define HW 16384
#define BATCH 8

typedef unsigned short u16;
typedef __attribute__((ext_vector_type(8))) short bfrag;   // 8 bf16 in 4 VGPRs
typedef __attribute__((ext_vector_type(4))) float ffrag;   // MFMA accumulator
typedef __attribute__((ext_vector_type(4))) float f4v;

// ---------------------------------------------------------------------------
__device__ __forceinline__ u16 f2bf(float f) {
  unsigned int u = __float_as_uint(f);
  u += 0x7FFFu + ((u >> 16) & 1u);
  return (u16)(u >> 16);
}
__device__ __forceinline__ float bf2f(u16 h) {
  return __uint_as_float(((unsigned int)h) << 16);
}
__device__ __forceinline__ ffrag mfma16(bfrag a, bfrag b, ffrag c) {
  return __builtin_amdgcn_mfma_f32_16x16x32_bf16(a, b, c, 0, 0, 0);
}

__device__ __forceinline__ float spline_eval(float x, const float* __restrict__ c,
                                             int K, float xmin, float xmax) {
  float step = (xmax - xmin) / (float)(K - 1);
  float t = (x - xmin) / step;
  float fidx = floorf(t);
  fidx = fminf(fmaxf(fidx, 0.0f), (float)(K - 2));
  int idx = (int)fidx;
  float frac = t - fidx;
  return c[idx] * (1.0f - frac) + c[idx + 1] * frac;
}
__device__ __forceinline__ float spline31(float x, const float* __restrict__ c) {
  float t = x * 10.0f;
  float fi = floorf(t);
  fi = fminf(fmaxf(fi, 0.0f), 29.0f);
  int i = (int)fi;
  float fr = t - fi;
  return c[i] * (1.0f - fr) + c[i + 1] * fr;
}

// ---------------------------------------------------------------------------
// Weight prep: OIHW fp32 -> MFMA B-fragment order, bf16 hi/lo planes. (r4-r10)
// ---------------------------------------------------------------------------
template<int KS, int CIW, int CO, int NTT, int NSLICE, int TAPS, int CHUNKS, bool TR>
__global__ void k_prepw(const float* __restrict__ W, u16* __restrict__ hi,
                        u16* __restrict__ lo) {
  int gid = blockIdx.x * 256 + threadIdx.x;
  const int total = NSLICE * CHUNKS * NTT * 64;
  if (gid >= total) return;
  int L = gid & 63;
  int rest = gid >> 6;
  int ntg = rest % NTT; rest /= NTT;
  int ch = rest % CHUNKS;
  int sl = rest / CHUNKS;
  int q = L >> 4, n = L & 15;
  int tap = ch * 4 + q;
  int co = ntg * 16 + n;
  int dh = tap / KS, dw = tap - dh * KS;
  for (int j = 0; j < 8; ++j) {
    int ci = sl * 8 + j;
    float v = 0.0f;
    if (tap < TAPS && co < CO) {
      if (TR)
        v = W[(((size_t)ci * CO + co) * KS + (KS - 1 - dh)) * KS + (KS - 1 - dw)];
      else
        v = W[(((size_t)co * CIW + ci) * KS + dh) * KS + dw];
    }
    u16 h = f2bf(v);
    hi[(size_t)gid * 8 + j] = h;
    lo[(size_t)gid * 8 + j] = f2bf(v - bf2f(h));
  }
}

// ---------------------------------------------------------------------------
// bconv (r6-verified): LDS-staged 1-term bf16 MFMA conv, CG path.
// EPI 0: outF NCHW fp32, co<8 | EPI 3: v*m^2 -> slice-major bf16
// ---------------------------------------------------------------------------
template<int KS, int SLICES, int TAPS, int CHUNKS, int NT, int NTT, int EPI>
__global__ __launch_bounds__(256) void bconv(
    const u16* __restrict__ in, const u16* __restrict__ wHi,
    float* __restrict__ outF, u16* __restrict__ outBf,
    const u16* __restrict__ mskc)
{
  constexpr int P  = KS / 2;
  constexpr int IW = 16 + 2 * P;
  constexpr int IH = 16 + 2 * P;

  __shared__ __align__(16) u16 sA[IH * IW * 8];

  const int tid = threadIdx.x;
  const int wv  = tid >> 6;
  const int L   = tid & 63;
  const int q   = L >> 4;
  const int n16 = L & 15;

  const int tx = blockIdx.x & 7, ty = blockIdx.x >> 3;
  const int w0 = tx * 16, h0 = ty * 16;
  const int bb = blockIdx.y;
  const int bz = blockIdx.z;

  ffrag acc[4][NT];
#pragma unroll
  for (int i = 0; i < 4; ++i)
#pragma unroll
    for (int t = 0; t < NT; ++t) acc[i][t] = (ffrag)0.0f;

  for (int slc = 0; slc < SLICES; ++slc) {
    __syncthreads();
    for (int e = tid; e < IH * IW; e += 256) {
      int ih = e / IW, iw = e - ih * IW;
      int gh = h0 + ih - P, gw = w0 + iw - P;
      f4v v = (f4v)0.0f;
      if (gh >= 0 && gh < 128 && gw >= 0 && gw < 128)
        v = *(const f4v*)(in + (((size_t)(bb * SLICES + slc) * HW) + gh * 128 + gw) * 8);
      *(f4v*)(sA + (size_t)e * 8) = v;
    }
    __syncthreads();

    const u16* wS = wHi + (size_t)slc * CHUNKS * NTT * 512;
    for (int ch = 0; ch < CHUNKS; ++ch) {
      int tap = ch * 4 + q;
      int dh = 0, dw = 0;
      if (tap < TAPS) { dh = tap / KS; dw = tap - dh * KS; }
      int toff = dh * IW + dw;
      bfrag A[4];
#pragma unroll
      for (int i = 0; i < 4; ++i)
        A[i] = *(const bfrag*)(sA + ((wv * 4 + i) * IW + n16 + toff) * 8);
#pragma unroll
      for (int t = 0; t < NT; ++t) {
        bfrag B = *(const bfrag*)(wS + ((size_t)ch * NTT + bz * NT + t) * 512 + L * 8);
#pragma unroll
        for (int i = 0; i < 4; ++i) acc[i][t] = mfma16(A[i], B, acc[i][t]);
      }
    }
  }

#pragma unroll
  for (int i = 0; i < 4; ++i) {
    const int h = h0 + wv * 4 + i;
#pragma unroll
    for (int t = 0; t < NT; ++t) {
      const int co = bz * (NT * 16) + t * 16 + n16;
#pragma unroll
      for (int r = 0; r < 4; ++r) {
        const int w = w0 + q * 4 + r;
        float v = acc[i][t][r];
        if (EPI == 0) {
          if (n16 < 8)
            outF[(((size_t)bb * 8 + n16) * 128 + h) * 128 + w] = v;
        } else if (EPI == 3) {
          size_t o = (((size_t)(bb * 16 + (co >> 3)) * HW) + h * 128 + w) * 8 + (co & 7);
          float m = bf2f(mskc[o]);
          outBf[o] = f2bf(v * m * m);
        }
      }
    }
  }
}

// ---------------------------------------------------------------------------
// mconv (r8-measured-best form): 3-term split MFMA conv, fp32 NHWC in,
// in-kernel hi/lo split during LDS staging.
// EPI 1: spline31(|v|) -> fp32 NHWC (stride 128)
// EPI 2: clip(spline31(sl*|v|),.01,1) -> mask_c bf16 slice-major
// ---------------------------------------------------------------------------
template<int KS, int CIN, int NSLICE, int TAPS, int CHUNKS,
         int TH, int MTW, int NT, int NTT, int EPI>
__global__ __launch_bounds__(256) void mconv(
    const float* __restrict__ inF,
    const u16* __restrict__ wHi, const u16* __restrict__ wLo,
    float* __restrict__ outF, u16* __restrict__ outBf,
    const float* __restrict__ sp, const float* __restrict__ sl,
    int binOfs, int boutOfs)
{
  constexpr int P  = KS / 2;
  constexpr int IW = 16 + 2 * P;
  constexpr int IH = TH + 2 * P;

  __shared__ __align__(16) u16 sHi[IH * IW * 8];
  __shared__ __align__(16) u16 sLo[IH * IW * 8];

  const int tid = threadIdx.x;
  const int wv  = tid >> 6;
  const int L   = tid & 63;
  const int q   = L >> 4;
  const int n16 = L & 15;

  const int tx = blockIdx.x & 7;
  const int ty = blockIdx.x >> 3;
  const int w0 = tx * 16, h0 = ty * TH;
  const int bin  = (int)blockIdx.y + binOfs;
  const int bout = (int)blockIdx.y + boutOfs;
  const int bz = blockIdx.z;

  ffrag acc[MTW][NT];
#pragma unroll
  for (int i = 0; i < MTW; ++i)
#pragma unroll
    for (int t = 0; t < NT; ++t) acc[i][t] = (ffrag)0.0f;

  for (int slc = 0; slc < NSLICE; ++slc) {
    __syncthreads();
    for (int e = tid; e < IH * IW; e += 256) {
      int ih = e / IW, iw = e - ih * IW;
      int gh = h0 + ih - P, gw = w0 + iw - P;
      float v[8];
      if (gh >= 0 && gh < 128 && gw >= 0 && gw < 128) {
        const float* s = inF + (((size_t)(bin * 128 + gh) * 128 + gw) * CIN + slc * 8);
        f4v a = *(const f4v*)s;
        f4v b2 = *(const f4v*)(s + 4);
        v[0] = a[0]; v[1] = a[1]; v[2] = a[2]; v[3] = a[3];
        v[4] = b2[0]; v[5] = b2[1]; v[6] = b2[2]; v[7] = b2[3];
      } else {
#pragma unroll
        for (int j = 0; j < 8; ++j) v[j] = 0.0f;
      }
#pragma unroll
      for (int j = 0; j < 8; ++j) {
        u16 hb = f2bf(v[j]);
        sHi[e * 8 + j] = hb;
        sLo[e * 8 + j] = f2bf(v[j] - bf2f(hb));
      }
    }
    __syncthreads();

    const u16* wHs = wHi + (size_t)slc * CHUNKS * NTT * 512;
    const u16* wLs = wLo + (size_t)slc * CHUNKS * NTT * 512;
    for (int ch = 0; ch < CHUNKS; ++ch) {
      int tap = ch * 4 + q;
      int dh = tap / KS;
      int dw = tap - dh * KS;
      int toff = (tap < TAPS) ? (dh * IW + dw) : 0;
      bfrag Ah[MTW], Al[MTW];
#pragma unroll
      for (int i = 0; i < MTW; ++i) {
        int a8 = ((wv * MTW + i) * IW + n16 + toff) * 8;
        Ah[i] = *(const bfrag*)(sHi + a8);
        Al[i] = *(const bfrag*)(sLo + a8);
      }
#pragma unroll
      for (int t = 0; t < NT; ++t) {
        size_t off = ((size_t)ch * NTT + bz * NT + t) * 512 + L * 8;
        bfrag Bh = *(const bfrag*)(wHs + off);
        bfrag Bl = *(const bfrag*)(wLs + off);
#pragma unroll
        for (int i = 0; i < MTW; ++i) {
          acc[i][t] = mfma16(Ah[i], Bh, acc[i][t]);
          acc[i][t] = mfma16(Ah[i], Bl, acc[i][t]);
          acc[i][t] = mfma16(Al[i], Bh, acc[i][t]);
        }
      }
    }
  }

#pragma unroll
  for (int i = 0; i < MTW; ++i) {
    const int h = h0 + wv * MTW + i;
#pragma unroll
    for (int t = 0; t < NT; ++t) {
      const int co = bz * (NT * 16) + t * 16 + n16;
#pragma unroll
      for (int r = 0; r < 4; ++r) {
        const int w = w0 + q * 4 + r;
        float v = acc[i][t][r];
        if (EPI == 1) {
          outF[(((size_t)bout * 128 + h) * 128 + w) * 128 + co] = spline31(fabsf(v), sp);
        } else if (EPI == 2) {
          float s = sl[bout * 128 + co];
          float x = spline31(s * fabsf(v), sp);
          x = fminf(fmaxf(x, 0.01f), 1.0f);
          size_t o = (((size_t)(bout * 16 + (co >> 3)) * HW) + h * 128 + w) * 8 + (co & 7);
          outBf[o] = f2bf(x);
        }
      }
    }
  }
}

// ---------------------------------------------------------------------------
// fused forward 1->4->8 (r5-r10 verified). OUT 0: fp32 NHWC8 | OUT 1: bf16 8ch
// ---------------------------------------------------------------------------
template<int OUT>
__global__ __launch_bounds__(256) void fused_fwd(
    const float* __restrict__ in, const float* __restrict__ wA,
    const float* __restrict__ wB, float* __restrict__ outF,
    u16* __restrict__ outBf)
{
  __shared__ float sX[32 * 48];
  __shared__ float sT4[4][24 * 41];
  __shared__ float sWA[81 * 4];
  __shared__ float sWB[4 * 81 * 8];

  const int tid = threadIdx.x;
  const int b   = blockIdx.z;
  const int h0  = (blockIdx.x >> 2) * 16;
  const int w0  = (blockIdx.x & 3) * 32;

  for (int e = tid; e < 32 * 48; e += 256) {
    int r = e / 48, c = e - r * 48;
    int gh = h0 - 8 + r, gw = w0 - 8 + c;
    float v = 0.0f;
    if (gh >= 0 && gh < 128 && gw >= 0 && gw < 128)
      v = in[(size_t)b * HW + gh * 128 + gw];
    sX[e] = v;
  }
  for (int e = tid; e < 324; e += 256) {
    int co = e & 3, tap = e >> 2;
    sWA[tap * 4 + co] = wA[co * 81 + tap];
  }
  for (int e = tid; e < 2592; e += 256) {
    int co = e & 7;
    int rest = e >> 3;
    int tap = rest % 81, ci = rest / 81;
    sWB[(ci * 81 + tap) * 8 + co] = wB[((size_t)co * 4 + ci) * 81 + tap];
  }
  __syncthreads();

  for (int e = tid; e < 960; e += 256) {
    int r = e / 40, c = e - r * 40;
    int gh = h0 - 4 + r, gw = w0 - 4 + c;
    float a0 = 0.0f, a1 = 0.0f, a2 = 0.0f, a3 = 0.0f;
    if (gh >= 0 && gh < 128 && gw >= 0 && gw < 128) {
      for (int kh = 0; kh < 9; ++kh) {
#pragma unroll
        for (int kw = 0; kw < 9; ++kw) {
          float x = sX[(r + kh) * 48 + (c + kw)];
          const float* wp = &sWA[(kh * 9 + kw) * 4];
          a0 += x * wp[0]; a1 += x * wp[1]; a2 += x * wp[2]; a3 += x * wp[3];
        }
      }
    }
    sT4[0][r * 41 + c] = a0;
    sT4[1][r * 41 + c] = a1;
    sT4[2][r * 41 + c] = a2;
    sT4[3][r * 41 + c] = a3;
  }
  __syncthreads();

  const int c  = tid & 31;
  const int r0 = tid >> 5;
  float acc[2][8];
#pragma unroll
  for (int j = 0; j < 2; ++j)
#pragma unroll
    for (int co = 0; co < 8; ++co) acc[j][co] = 0.0f;

  for (int ci = 0; ci < 4; ++ci) {
    const float* t4c = sT4[ci];
    for (int kh = 0; kh < 9; ++kh) {
#pragma unroll
      for (int kw = 0; kw < 9; ++kw) {
        float x0 = t4c[(r0 + kh) * 41 + c + kw];
        float x1 = t4c[(r0 + 8 + kh) * 41 + c + kw];
        const float* wp = &sWB[(ci * 81 + kh * 9 + kw) * 8];
#pragma unroll
        for (int co = 0; co < 8; ++co) {
          acc[0][co] += x0 * wp[co];
          acc[1][co] += x1 * wp[co];
        }
      }
    }
  }

#pragma unroll
  for (int j = 0; j < 2; ++j) {
    const int h = h0 + r0 + 8 * j;
    const int w = w0 + c;
#pragma unroll
    for (int co = 0; co < 8; ++co) {
      float v = acc[j][co];
      if (OUT == 0)
        outF[(((size_t)b * 128 + h) * 128 + w) * 8 + co] = v;
      else
        outBf[((size_t)b * HW + h * 128 + w) * 8 + co] = f2bf(v);
    }
  }
}

// ---------------------------------------------------------------------------
// fp32 direct conv, transposed small shapes (r2/r6/r10-verified core).
// EPI 0: NCHW fp32 | EPI 5: out = (aux + lam*v)/(1+lam), CO==1
// ---------------------------------------------------------------------------
template<int KS, int CI, int CO, int CIC, int COT, int TH, int EPI, bool TR>
__global__ __launch_bounds__(256) void conv_k(
    const float* __restrict__ in, const float* __restrict__ wt,
    float* __restrict__ out, const float* __restrict__ aux,
    const float* __restrict__ sl)
{
  constexpr int P  = KS / 2;
  constexpr int TW = 32;
  constexpr int IH = TH + 2 * P;
  constexpr int IW = TW + 2 * P;
  constexpr int RPT = TH / 8;
  constexpr int NCH = CI / CIC;
  static_assert(CIC * NCH == CI, "channel split mismatch");

  __shared__ float sIn[CIC * IH * IW];
  __shared__ float sW[CIC * KS * KS * COT];

  const int tid = threadIdx.x;
  const int nTW = 128 / TW;
  const int th0 = (blockIdx.x / nTW) * TH;
  const int tw0 = (blockIdx.x % nTW) * TW;
  const int b   = blockIdx.z;

  float acc[RPT][COT];
#pragma unroll
  for (int j = 0; j < RPT; ++j)
#pragma unroll
    for (int co = 0; co < COT; ++co) acc[j][co] = 0.0f;

  const int c  = tid & 31;
  const int r0 = tid >> 5;

  for (int ch = 0; ch < NCH; ++ch) {
    const int ci0 = ch * CIC;
    __syncthreads();
    for (int e = tid; e < CIC * IH * IW; e += 256) {
      int ci  = e / (IH * IW);
      int rem = e - ci * (IH * IW);
      int ih  = rem / IW;
      int iw  = rem - ih * IW;
      int gh = th0 + ih - P, gw = tw0 + iw - P;
      float v = 0.0f;
      if (gh >= 0 && gh < 128 && gw >= 0 && gw < 128)
        v = in[((size_t)(b * CI + ci0 + ci) * 128 + gh) * 128 + gw];
      sIn[e] = v;
    }
    for (int e = tid; e < CIC * KS * KS * COT; e += 256) {
      int co = e & (COT - 1);
      int k  = e / COT;
      int ci = k / (KS * KS);
      int kk = k - ci * (KS * KS);
      int kh = kk / KS, kw = kk - kh * KS;
      float wv;
      if (!TR)
        wv = wt[(((size_t)co * CI + ci0 + ci) * KS + kh) * KS + kw];
      else
        wv = wt[(((size_t)(ci0 + ci) * CO + co) * KS + (KS - 1 - kh)) * KS + (KS - 1 - kw)];
      sW[e] = wv;
    }
    __syncthreads();

    for (int ci = 0; ci < CIC; ++ci) {
      for (int kh = 0; kh < KS; ++kh) {
        const float* inb = &sIn[(ci * IH + r0 + kh) * IW + c];
        const float* wb  = &sW[(ci * KS + kh) * KS * COT];
#pragma unroll
        for (int kw = 0; kw < KS; ++kw) {
          float xv[RPT];
#pragma unroll
          for (int j = 0; j < RPT; ++j) xv[j] = inb[8 * j * IW + kw];
#pragma unroll
          for (int co = 0; co < COT; ++co) {
            float wv = wb[kw * COT + co];
#pragma unroll
            for (int j = 0; j < RPT; ++j) acc[j][co] += xv[j] * wv;
          }
        }
      }
    }
  }

#pragma unroll
  for (int j = 0; j < RPT; ++j) {
    const int h = th0 + r0 + 8 * j;
    const int w = tw0 + c;
#pragma unroll
    for (int co = 0; co < COT; ++co) {
      float v = acc[j][co];
      if (EPI == 5) {
        size_t o = ((size_t)b * 128 + h) * 128 + w;
        float l = sl[b];
        out[o] = (aux[o] + l * v) / (1.0f + l);
      } else {
        out[((size_t)(b * CO + co) * 128 + h) * 128 + w] = v;
      }
    }
  }
}

// ---------------------------------------------------------------------------
// helpers
// ---------------------------------------------------------------------------
__global__ void k_scalars(const float* __restrict__ sigma, const float* __restrict__ c_lam,
                          const float* __restrict__ c_scal, float* __restrict__ lam,
                          float* __restrict__ scal) {
  int tid = threadIdx.x;
  if (tid < BATCH) lam[tid] = spline_eval(sigma[tid], c_lam, 53, -1.0f, 51.0f);
  for (int j = tid; j < BATCH * 128; j += 256) {
    int b = j >> 7, chn = j & 127;
    float s = sigma[b];
    scal[j] = expf(spline_eval(s, c_scal + chn * 14, 14, -1.0f, 51.0f)) / (s + 1e-5f);
  }
}

__global__ void k_binit(const float* __restrict__ y, const float* __restrict__ lam,
                        float* __restrict__ bimg, float* __restrict__ x) {
  int i = blockIdx.x * 256 + threadIdx.x;
  int b = i >> 14;
  bimg[i] = y[i] / (1.0f + lam[b]);
  x[i] = 0.0f;
}

// mask for c_k = 0: every conv chain output is exactly 0 in fp32 (no biases),
// so mask = clip(spline31(0), .01, 1) = clip(c_sp3[0], .01, 1) everywhere.
__global__ void k_fillmask(const float* __restrict__ c_sp3, u16* __restrict__ mask_c) {
  u16 hv = f2bf(fminf(fmaxf(c_sp3[0], 0.01f), 1.0f));
  u16 tmp[8];
#pragma unroll
  for (int j = 0; j < 8; ++j) tmp[j] = hv;
  size_t i = ((size_t)blockIdx.x * 256 + threadIdx.x) * 8;   // 16777216 total
  *(f4v*)(mask_c + i) = *(const f4v*)tmp;
}

__global__ void k_dot(const float* __restrict__ a, const float* __restrict__ bv,
                      float* __restrict__ out) {
  __shared__ float s[256];
  int b = blockIdx.x;
  float sum = 0.0f;
  for (int i = threadIdx.x; i < HW; i += 256) sum += a[b * HW + i] * bv[b * HW + i];
  s[threadIdx.x] = sum;
  __syncthreads();
  for (int st = 128; st > 0; st >>= 1) {
    if (threadIdx.x < st) s[threadIdx.x] += s[threadIdx.x + st];
    __syncthreads();
  }
  if (threadIdx.x == 0) out[b] = s[0];
}

// CG init with BtB(x0=0) = 0 exactly: r = p = bimg; rn = <bimg,bimg>.
__global__ void k_cg0b(const float* __restrict__ bimg, float* __restrict__ r,
                       float* __restrict__ p, float* __restrict__ rn) {
  __shared__ float s[256];
  int b = blockIdx.x;
  size_t base = (size_t)b << 14;
  float local = 0.0f;
  for (int i = threadIdx.x; i < HW; i += 256) {
    float v = bimg[base + i];
    r[base + i] = v;
    p[base + i] = v;
    local += v * v;
  }
  s[threadIdx.x] = local;
  __syncthreads();
  for (int st = 128; st > 0; st >>= 1) {
    if (threadIdx.x < st) s[threadIdx.x] += s[threadIdx.x + st];
    __syncthreads();
  }
  if (threadIdx.x == 0) rn[b] = s[0];
}

// r = bimg - Bp; p = r; rn[b] = <r,r>   (r8-verified)
__global__ void k_cg0(const float* __restrict__ bimg, const float* __restrict__ Bp,
                      float* __restrict__ r, float* __restrict__ p,
                      float* __restrict__ rn) {
  __shared__ float s[256];
  int b = blockIdx.x;
  size_t base = (size_t)b << 14;
  float local = 0.0f;
  for (int i = threadIdx.x; i < HW; i += 256) {
    float v = bimg[base + i] - Bp[base + i];
    r[base + i] = v;
    p[base + i] = v;
    local += v * v;
  }
  s[threadIdx.x] = local;
  __syncthreads();
  for (int st = 128; st > 0; st >>= 1) {
    if (threadIdx.x < st) s[threadIdx.x] += s[threadIdx.x + st];
    __syncthreads();
  }
  if (threadIdx.x == 0) rn[b] = s[0];
}

// alpha-update + rn2 reduce + beta + p-update (r8/r10-verified); optional x->xout.
__global__ void k_cg2(float* __restrict__ x, float* __restrict__ r,
                      float* __restrict__ p, const float* __restrict__ Bp,
                      float* __restrict__ rn, const float* __restrict__ den,
                      float* __restrict__ xout) {
  __shared__ float s[256];
  int b = blockIdx.x;
  size_t base = (size_t)b << 14;
  float rnb = rn[b];
  bool act = rnb > 1e-6f;
  float alpha = act ? rnb / den[b] : 0.0f;
  float local = 0.0f;
  for (int i = threadIdx.x; i < HW; i += 256) {
    float pv = p[base + i];
    float xv = x[base + i] + alpha * pv;
    x[base + i] = xv;
    if (xout) xout[base + i] = xv;
    float rr = r[base + i] - alpha * Bp[base + i];
    r[base + i] = rr;
    local += rr * rr;
  }
  s[threadIdx.x] = local;
  __syncthreads();
  for (int st = 128; st > 0; st >>= 1) {
    if (threadIdx.x < st) s[threadIdx.x] += s[threadIdx.x + st];
    __syncthreads();
  }
  float rn2 = s[0];
  float beta = act ? rn2 / rnb : 0.0f;
  if (threadIdx.x == 0) rn[b] = rn2;
  for (int i = threadIdx.x; i < HW; i += 256)
    p[base + i] = r[base + i] + beta * p[base + i];
}

// ---------------------------------------------------------------------------
extern "C" void kernel_launch(void* const* d_in, const int* in_sizes, int n_in_,
                              void* d_out, int out_size, void* d_ws, size_t ws_size,
                              hipStream_t stream) {
  const float* y      = (const float*)d_in[0];
  const float* sigma  = (const float*)d_in[1];
  const float* w1_0   = (const float*)d_in[2];
  const float* w1_1   = (const float*)d_in[3];
  const float* w1_2   = (const float*)d_in[4];
  const float* m1_0   = (const float*)d_in[5];
  const float* m1_1   = (const float*)d_in[6];
  const float* m1_2   = (const float*)d_in[7];
  const float* m2_w   = (const float*)d_in[8];
  const float* m3_w   = (const float*)d_in[9];
  const float* c_sp1  = (const float*)d_in[10];
  const float* c_sp2  = (const float*)d_in[11];
  const float* c_sp3  = (const float*)d_in[12];
  const float* c_lam  = (const float*)d_in[13];
  const float* c_scal = (const float*)d_in[14];
  // n_out = 2, n_in = 6 fixed by setup_inputs

  char* cur = (char*)d_ws;
  auto alloc = [&](size_t bytes) {
    char* p = cur;
    cur += (bytes + 255) & ~(size_t)255;
    return p;
  };

  // weight fragments (~3 MB)
  u16* wA_hi  = (u16*)alloc(86016 * 2);
  u16* wA_lo  = (u16*)alloc(86016 * 2);
  u16* wAm_hi = (u16*)alloc(86016 * 2);
  u16* wAm_lo = (u16*)alloc(86016 * 2);
  u16* wB_hi  = (u16*)alloc(172032 * 2);
  u16* wB_lo  = (u16*)alloc(172032 * 2);
  u16* wC2_hi = (u16*)alloc(196608 * 2);
  u16* wC2_lo = (u16*)alloc(196608 * 2);
  u16* wC3_hi = (u16*)alloc(196608 * 2);
  u16* wC3_lo = (u16*)alloc(196608 * 2);

  // region1 (67.1 MB): mask phase = P1f fp32 NHWC128; CG = big2c bf16 slice-major
  char* region1 = alloc((size_t)16777216 * 4);
  float* P1f   = (float*)region1;
  u16*   big2c = (u16*)region1;
  // mask_c bf16 slice-major [8][16][HW][8] (33.5 MB)
  u16* mask_c = (u16*)alloc((size_t)16777216 * 2);
  // region2 (33.6 MB): mask phase = P2s fp32 NHWC128 x 4 batches; CG = t8n + t4
  char* region2 = alloc((size_t)4 * 128 * 128 * 128 * 4);
  float* P2s = (float*)region2;
  float* t8n = (float*)region2;                       // 4.2 MB NCHW8 fp32
  float* t4  = (float*)(region2 + 4194304);           // 2.1 MB NCHW4 fp32
  // region3 (4.2 MB): mask phase = t8f fp32 NHWC8; CG = t8c bf16 slice-major
  char* region3 = alloc((size_t)1048576 * 4);
  float* t8f = (float*)region3;
  u16*   t8c = (u16*)region3;

  float* bimg = (float*)alloc(131072 * 4);
  float* xbuf = (float*)alloc(131072 * 4);
  float* rbuf = (float*)alloc(131072 * 4);
  float* pbuf = (float*)alloc(131072 * 4);
  float* Bp   = (float*)alloc(131072 * 4);
  float* lam  = (float*)alloc(8 * 4);
  float* scal = (float*)alloc(1024 * 4);
  float* rn   = (float*)alloc(8 * 4);
  float* den  = (float*)alloc(8 * 4);
  // total ~144 MB (r8/r10 passing layout)

  const dim3 blk(256);

  k_prepw<9, 8, 128, 8, 1, 81, 21, false><<<dim3(42), blk, 0, stream>>>(w1_2, wA_hi, wA_lo);
  k_prepw<9, 8, 128, 8, 1, 81, 21, false><<<dim3(42), blk, 0, stream>>>(m1_2, wAm_hi, wAm_lo);
  k_prepw<9, 8, 8, 1, 16, 81, 21, true><<<dim3(84), blk, 0, stream>>>(w1_2, wB_hi, wB_lo);
  k_prepw<3, 128, 128, 8, 16, 9, 3, false><<<dim3(96), blk, 0, stream>>>(m2_w, wC2_hi, wC2_lo);
  k_prepw<3, 128, 128, 8, 16, 9, 3, false><<<dim3(96), blk, 0, stream>>>(m3_w, wC3_hi, wC3_lo);

  k_scalars<<<dim3(1), blk, 0, stream>>>(sigma, c_lam, c_scal, lam, scal);
  k_binit<<<dim3(512), blk, 0, stream>>>(y, lam, bimg, xbuf);

  // CG path: r6-champion configuration
  auto BtB = [&](const float* vin, float* vout) {
    fused_fwd<1><<<dim3(32, 1, 8), blk, 0, stream>>>(vin, w1_0, w1_1, nullptr, t8c);
    bconv<9, 1, 81, 21, 2, 8, 3><<<dim3(64, 8, 4), blk, 0, stream>>>(
        t8c, wA_hi, nullptr, big2c, mask_c);
    bconv<9, 16, 81, 21, 1, 1, 0><<<dim3(64, 8, 1), blk, 0, stream>>>(
        big2c, wB_hi, t8n, nullptr, nullptr);
    conv_k<9, 8, 4, 2, 4, 16, 0, true><<<dim3(32, 1, 8), blk, 0, stream>>>(
        t8n, w1_1, t4, nullptr, nullptr);
    conv_k<9, 4, 1, 1, 1, 16, 5, true><<<dim3(32, 1, 8), blk, 0, stream>>>(
        t4, w1_0, vout, vin, lam);
  };

  // ================= outer 0: c_k = 0 =================
  // mask = cal_mask(0) = constant; BtB(x0=0) = 0 exactly -> r0 = p0 = bimg
  k_fillmask<<<dim3(8192), blk, 0, stream>>>(c_sp3, mask_c);
  k_cg0b<<<dim3(8), blk, 0, stream>>>(bimg, rbuf, pbuf, rn);
  for (int it = 0; it < 6; ++it) {
    BtB(pbuf, Bp);
    k_dot<<<dim3(8), blk, 0, stream>>>(pbuf, Bp, den);
    k_cg2<<<dim3(8), blk, 0, stream>>>(xbuf, rbuf, pbuf, Bp, rn, den, nullptr);
  }

  // ================= outer 1 =================
  // mask = cal_mask(c_k); 3-term fp32 path (r8-measured-best)
  fused_fwd<0><<<dim3(32, 1, 8), blk, 0, stream>>>(xbuf, m1_0, m1_1, t8f, nullptr);
  mconv<9, 8, 1, 81, 21, 16, 4, 2, 8, 1><<<dim3(64, 8, 4), blk, 0, stream>>>(
      t8f, wAm_hi, wAm_lo, P1f, nullptr, c_sp1, nullptr, 0, 0);
  for (int bc = 0; bc < 2; ++bc) {
    mconv<3, 128, 16, 9, 3, 16, 4, 2, 8, 1><<<dim3(64, 4, 4), blk, 0, stream>>>(
        P1f, wC2_hi, wC2_lo, P2s, nullptr, c_sp2, nullptr, bc * 4, 0);
    mconv<3, 128, 16, 9, 3, 16, 4, 2, 8, 2><<<dim3(64, 4, 4), blk, 0, stream>>>(
        P2s, wC3_hi, wC3_lo, nullptr, mask_c, c_sp3, scal, 0, bc * 4);
  }

  BtB(xbuf, Bp);
  k_cg0<<<dim3(8), blk, 0, stream>>>(bimg, Bp, rbuf, pbuf, rn);
  for (int it = 0; it < 6; ++it) {
    BtB(pbuf, Bp);
    k_dot<<<dim3(8), blk, 0, stream>>>(pbuf, Bp, den);
    float* xout = (it == 5) ? (float*)d_out : nullptr;
    k_cg2<<<dim3(8), blk, 0, stream>>>(xbuf, rbuf, pbuf, Bp, rn, den, xout);
  }
}

// Round 12
// 3034.572 us; speedup vs baseline: 1.2410x; 1.0074x over previous
//
#include <hip/hip_runtime.h>

#define HW 16384
#define BATCH 8

typedef unsigned short u16;
typedef __attribute__((ext_vector_type(8))) short bfrag;   // 8 bf16 in 4 VGPRs
typedef __attribute__((ext_vector_type(4))) float ffrag;   // MFMA accumulator
typedef __attribute__((ext_vector_type(4))) float f4v;

// ---------------------------------------------------------------------------
__device__ __forceinline__ u16 f2bf(float f) {
  unsigned int u = __float_as_uint(f);
  u += 0x7FFFu + ((u >> 16) & 1u);
  return (u16)(u >> 16);
}
__device__ __forceinline__ float bf2f(u16 h) {
  return __uint_as_float(((unsigned int)h) << 16);
}
__device__ __forceinline__ ffrag mfma16(bfrag a, bfrag b, ffrag c) {
  return __builtin_amdgcn_mfma_f32_16x16x32_bf16(a, b, c, 0, 0, 0);
}

__device__ __forceinline__ float spline_eval(float x, const float* __restrict__ c,
                                             int K, float xmin, float xmax) {
  float step = (xmax - xmin) / (float)(K - 1);
  float t = (x - xmin) / step;
  float fidx = floorf(t);
  fidx = fminf(fmaxf(fidx, 0.0f), (float)(K - 2));
  int idx = (int)fidx;
  float frac = t - fidx;
  return c[idx] * (1.0f - frac) + c[idx + 1] * frac;
}
__device__ __forceinline__ float spline31(float x, const float* __restrict__ c) {
  float t = x * 10.0f;
  float fi = floorf(t);
  fi = fminf(fmaxf(fi, 0.0f), 29.0f);
  int i = (int)fi;
  float fr = t - fi;
  return c[i] * (1.0f - fr) + c[i + 1] * fr;
}

// ---------------------------------------------------------------------------
// Weight prep: OIHW fp32 -> MFMA B-fragment order, bf16 hi/lo planes. (r4-r11)
// ---------------------------------------------------------------------------
template<int KS, int CIW, int CO, int NTT, int NSLICE, int TAPS, int CHUNKS, bool TR>
__global__ void k_prepw(const float* __restrict__ W, u16* __restrict__ hi,
                        u16* __restrict__ lo) {
  int gid = blockIdx.x * 256 + threadIdx.x;
  const int total = NSLICE * CHUNKS * NTT * 64;
  if (gid >= total) return;
  int L = gid & 63;
  int rest = gid >> 6;
  int ntg = rest % NTT; rest /= NTT;
  int ch = rest % CHUNKS;
  int sl = rest / CHUNKS;
  int q = L >> 4, n = L & 15;
  int tap = ch * 4 + q;
  int co = ntg * 16 + n;
  int dh = tap / KS, dw = tap - dh * KS;
  for (int j = 0; j < 8; ++j) {
    int ci = sl * 8 + j;
    float v = 0.0f;
    if (tap < TAPS && co < CO) {
      if (TR)
        v = W[(((size_t)ci * CO + co) * KS + (KS - 1 - dh)) * KS + (KS - 1 - dw)];
      else
        v = W[(((size_t)co * CIW + ci) * KS + dh) * KS + dw];
    }
    u16 h = f2bf(v);
    hi[(size_t)gid * 8 + j] = h;
    lo[(size_t)gid * 8 + j] = f2bf(v - bf2f(h));
  }
}

// ---------------------------------------------------------------------------
// bconv (r6-verified core + KSPLIT): LDS-staged 1-term bf16 MFMA conv.
// KSPLIT>1: blockIdx.z = K-slice group (co-group fixed 0), partial fp32 out.
// EPI 3: v*m^2 -> slice-major bf16 (128ch)
// EPI 5: partial fp32, co<8 -> part[(bz*BATCH+bb)*HW + px]*8 + co
// ---------------------------------------------------------------------------
template<int KS, int SLICES, int TAPS, int CHUNKS, int NT, int NTT, int KSPLIT, int EPI>
__global__ __launch_bounds__(256) void bconv(
    const u16* __restrict__ in, const u16* __restrict__ wHi,
    float* __restrict__ outF, u16* __restrict__ outBf,
    const u16* __restrict__ mskc)
{
  constexpr int P   = KS / 2;
  constexpr int IW  = 16 + 2 * P;
  constexpr int IH  = 16 + 2 * P;
  constexpr int SPB = SLICES / KSPLIT;

  __shared__ __align__(16) u16 sA[IH * IW * 8];

  const int tid = threadIdx.x;
  const int wv  = tid >> 6;
  const int L   = tid & 63;
  const int q   = L >> 4;
  const int n16 = L & 15;

  const int tx = blockIdx.x & 7, ty = blockIdx.x >> 3;
  const int w0 = tx * 16, h0 = ty * 16;
  const int bb = blockIdx.y;
  const int bz = blockIdx.z;
  const int slc0 = (KSPLIT > 1) ? bz * SPB : 0;
  const int cog  = (KSPLIT > 1) ? 0 : bz;

  ffrag acc[4][NT];
#pragma unroll
  for (int i = 0; i < 4; ++i)
#pragma unroll
    for (int t = 0; t < NT; ++t) acc[i][t] = (ffrag)0.0f;

  for (int s = 0; s < SPB; ++s) {
    const int slc = slc0 + s;
    __syncthreads();
    for (int e = tid; e < IH * IW; e += 256) {
      int ih = e / IW, iw = e - ih * IW;
      int gh = h0 + ih - P, gw = w0 + iw - P;
      f4v v = (f4v)0.0f;
      if (gh >= 0 && gh < 128 && gw >= 0 && gw < 128)
        v = *(const f4v*)(in + (((size_t)(bb * SLICES + slc) * HW) + gh * 128 + gw) * 8);
      *(f4v*)(sA + (size_t)e * 8) = v;
    }
    __syncthreads();

    const u16* wS = wHi + (size_t)slc * CHUNKS * NTT * 512;
    for (int ch = 0; ch < CHUNKS; ++ch) {
      int tap = ch * 4 + q;
      int dh = 0, dw = 0;
      if (tap < TAPS) { dh = tap / KS; dw = tap - dh * KS; }
      int toff = dh * IW + dw;
      bfrag A[4];
#pragma unroll
      for (int i = 0; i < 4; ++i)
        A[i] = *(const bfrag*)(sA + ((wv * 4 + i) * IW + n16 + toff) * 8);
#pragma unroll
      for (int t = 0; t < NT; ++t) {
        bfrag B = *(const bfrag*)(wS + ((size_t)ch * NTT + cog * NT + t) * 512 + L * 8);
#pragma unroll
        for (int i = 0; i < 4; ++i) acc[i][t] = mfma16(A[i], B, acc[i][t]);
      }
    }
  }

#pragma unroll
  for (int i = 0; i < 4; ++i) {
    const int h = h0 + wv * 4 + i;
#pragma unroll
    for (int t = 0; t < NT; ++t) {
      const int co = cog * (NT * 16) + t * 16 + n16;
#pragma unroll
      for (int r = 0; r < 4; ++r) {
        const int w = w0 + q * 4 + r;
        float v = acc[i][t][r];
        if (EPI == 3) {
          size_t o = (((size_t)(bb * 16 + (co >> 3)) * HW) + h * 128 + w) * 8 + (co & 7);
          float m = bf2f(mskc[o]);
          outBf[o] = f2bf(v * m * m);
        } else if (EPI == 5) {
          if (n16 < 8)
            outF[(((size_t)bz * BATCH + bb) * HW + h * 128 + w) * 8 + n16] = v;
        }
      }
    }
  }
}

// ---------------------------------------------------------------------------
// combine 4 fp32 partials [z][b][px][8] -> bf16 slice-major t8v [b][px][8]
// ---------------------------------------------------------------------------
__global__ void k_combine8(const float* __restrict__ part, u16* __restrict__ t8v) {
  size_t px = (size_t)blockIdx.x * 256 + threadIdx.x;  // 131072 total
  float s[8];
#pragma unroll
  for (int j = 0; j < 8; ++j) s[j] = 0.0f;
#pragma unroll
  for (int z = 0; z < 4; ++z) {
    const float* p = part + (size_t)z * 1048576 + px * 8;
    f4v a = *(const f4v*)p;
    f4v b = *(const f4v*)(p + 4);
    s[0] += a[0]; s[1] += a[1]; s[2] += a[2]; s[3] += a[3];
    s[4] += b[0]; s[5] += b[1]; s[6] += b[2]; s[7] += b[3];
  }
  u16 o[8];
#pragma unroll
  for (int j = 0; j < 8; ++j) o[j] = f2bf(s[j]);
  *(f4v*)(t8v + px * 8) = *(const f4v*)o;
}

// ---------------------------------------------------------------------------
// mconv (r8/r11-measured-best): 3-term split MFMA conv, fp32 NHWC in.
// EPI 1: spline31(|v|) -> fp32 NHWC | EPI 2: clip spline -> mask_c bf16
// ---------------------------------------------------------------------------
template<int KS, int CIN, int NSLICE, int TAPS, int CHUNKS,
         int TH, int MTW, int NT, int NTT, int EPI>
__global__ __launch_bounds__(256) void mconv(
    const float* __restrict__ inF,
    const u16* __restrict__ wHi, const u16* __restrict__ wLo,
    float* __restrict__ outF, u16* __restrict__ outBf,
    const float* __restrict__ sp, const float* __restrict__ sl,
    int binOfs, int boutOfs)
{
  constexpr int P  = KS / 2;
  constexpr int IW = 16 + 2 * P;
  constexpr int IH = TH + 2 * P;

  __shared__ __align__(16) u16 sHi[IH * IW * 8];
  __shared__ __align__(16) u16 sLo[IH * IW * 8];

  const int tid = threadIdx.x;
  const int wv  = tid >> 6;
  const int L   = tid & 63;
  const int q   = L >> 4;
  const int n16 = L & 15;

  const int tx = blockIdx.x & 7;
  const int ty = blockIdx.x >> 3;
  const int w0 = tx * 16, h0 = ty * TH;
  const int bin  = (int)blockIdx.y + binOfs;
  const int bout = (int)blockIdx.y + boutOfs;
  const int bz = blockIdx.z;

  ffrag acc[MTW][NT];
#pragma unroll
  for (int i = 0; i < MTW; ++i)
#pragma unroll
    for (int t = 0; t < NT; ++t) acc[i][t] = (ffrag)0.0f;

  for (int slc = 0; slc < NSLICE; ++slc) {
    __syncthreads();
    for (int e = tid; e < IH * IW; e += 256) {
      int ih = e / IW, iw = e - ih * IW;
      int gh = h0 + ih - P, gw = w0 + iw - P;
      float v[8];
      if (gh >= 0 && gh < 128 && gw >= 0 && gw < 128) {
        const float* s = inF + (((size_t)(bin * 128 + gh) * 128 + gw) * CIN + slc * 8);
        f4v a = *(const f4v*)s;
        f4v b2 = *(const f4v*)(s + 4);
        v[0] = a[0]; v[1] = a[1]; v[2] = a[2]; v[3] = a[3];
        v[4] = b2[0]; v[5] = b2[1]; v[6] = b2[2]; v[7] = b2[3];
      } else {
#pragma unroll
        for (int j = 0; j < 8; ++j) v[j] = 0.0f;
      }
#pragma unroll
      for (int j = 0; j < 8; ++j) {
        u16 hb = f2bf(v[j]);
        sHi[e * 8 + j] = hb;
        sLo[e * 8 + j] = f2bf(v[j] - bf2f(hb));
      }
    }
    __syncthreads();

    const u16* wHs = wHi + (size_t)slc * CHUNKS * NTT * 512;
    const u16* wLs = wLo + (size_t)slc * CHUNKS * NTT * 512;
    for (int ch = 0; ch < CHUNKS; ++ch) {
      int tap = ch * 4 + q;
      int dh = tap / KS;
      int dw = tap - dh * KS;
      int toff = (tap < TAPS) ? (dh * IW + dw) : 0;
      bfrag Ah[MTW], Al[MTW];
#pragma unroll
      for (int i = 0; i < MTW; ++i) {
        int a8 = ((wv * MTW + i) * IW + n16 + toff) * 8;
        Ah[i] = *(const bfrag*)(sHi + a8);
        Al[i] = *(const bfrag*)(sLo + a8);
      }
#pragma unroll
      for (int t = 0; t < NT; ++t) {
        size_t off = ((size_t)ch * NTT + bz * NT + t) * 512 + L * 8;
        bfrag Bh = *(const bfrag*)(wHs + off);
        bfrag Bl = *(const bfrag*)(wLs + off);
#pragma unroll
        for (int i = 0; i < MTW; ++i) {
          acc[i][t] = mfma16(Ah[i], Bh, acc[i][t]);
          acc[i][t] = mfma16(Ah[i], Bl, acc[i][t]);
          acc[i][t] = mfma16(Al[i], Bh, acc[i][t]);
        }
      }
    }
  }

#pragma unroll
  for (int i = 0; i < MTW; ++i) {
    const int h = h0 + wv * MTW + i;
#pragma unroll
    for (int t = 0; t < NT; ++t) {
      const int co = bz * (NT * 16) + t * 16 + n16;
#pragma unroll
      for (int r = 0; r < 4; ++r) {
        const int w = w0 + q * 4 + r;
        float v = acc[i][t][r];
        if (EPI == 1) {
          outF[(((size_t)bout * 128 + h) * 128 + w) * 128 + co] = spline31(fabsf(v), sp);
        } else if (EPI == 2) {
          float s = sl[bout * 128 + co];
          float x = spline31(s * fabsf(v), sp);
          x = fminf(fmaxf(x, 0.01f), 1.0f);
          size_t o = (((size_t)(bout * 16 + (co >> 3)) * HW) + h * 128 + w) * 8 + (co & 7);
          outBf[o] = f2bf(x);
        }
      }
    }
  }
}

// ---------------------------------------------------------------------------
// fused forward 1->4->8 (r5-r11 verified). OUT 0: fp32 NHWC8 | OUT 1: bf16 8ch
// ---------------------------------------------------------------------------
template<int OUT>
__global__ __launch_bounds__(256) void fused_fwd(
    const float* __restrict__ in, const float* __restrict__ wA,
    const float* __restrict__ wB, float* __restrict__ outF,
    u16* __restrict__ outBf)
{
  __shared__ float sX[32 * 48];
  __shared__ float sT4[4][24 * 41];
  __shared__ float sWA[81 * 4];
  __shared__ float sWB[4 * 81 * 8];

  const int tid = threadIdx.x;
  const int b   = blockIdx.z;
  const int h0  = (blockIdx.x >> 2) * 16;
  const int w0  = (blockIdx.x & 3) * 32;

  for (int e = tid; e < 32 * 48; e += 256) {
    int r = e / 48, c = e - r * 48;
    int gh = h0 - 8 + r, gw = w0 - 8 + c;
    float v = 0.0f;
    if (gh >= 0 && gh < 128 && gw >= 0 && gw < 128)
      v = in[(size_t)b * HW + gh * 128 + gw];
    sX[e] = v;
  }
  for (int e = tid; e < 324; e += 256) {
    int co = e & 3, tap = e >> 2;
    sWA[tap * 4 + co] = wA[co * 81 + tap];
  }
  for (int e = tid; e < 2592; e += 256) {
    int co = e & 7;
    int rest = e >> 3;
    int tap = rest % 81, ci = rest / 81;
    sWB[(ci * 81 + tap) * 8 + co] = wB[((size_t)co * 4 + ci) * 81 + tap];
  }
  __syncthreads();

  for (int e = tid; e < 960; e += 256) {
    int r = e / 40, c = e - r * 40;
    int gh = h0 - 4 + r, gw = w0 - 4 + c;
    float a0 = 0.0f, a1 = 0.0f, a2 = 0.0f, a3 = 0.0f;
    if (gh >= 0 && gh < 128 && gw >= 0 && gw < 128) {
      for (int kh = 0; kh < 9; ++kh) {
#pragma unroll
        for (int kw = 0; kw < 9; ++kw) {
          float x = sX[(r + kh) * 48 + (c + kw)];
          const float* wp = &sWA[(kh * 9 + kw) * 4];
          a0 += x * wp[0]; a1 += x * wp[1]; a2 += x * wp[2]; a3 += x * wp[3];
        }
      }
    }
    sT4[0][r * 41 + c] = a0;
    sT4[1][r * 41 + c] = a1;
    sT4[2][r * 41 + c] = a2;
    sT4[3][r * 41 + c] = a3;
  }
  __syncthreads();

  const int c  = tid & 31;
  const int r0 = tid >> 5;
  float acc[2][8];
#pragma unroll
  for (int j = 0; j < 2; ++j)
#pragma unroll
    for (int co = 0; co < 8; ++co) acc[j][co] = 0.0f;

  for (int ci = 0; ci < 4; ++ci) {
    const float* t4c = sT4[ci];
    for (int kh = 0; kh < 9; ++kh) {
#pragma unroll
      for (int kw = 0; kw < 9; ++kw) {
        float x0 = t4c[(r0 + kh) * 41 + c + kw];
        float x1 = t4c[(r0 + 8 + kh) * 41 + c + kw];
        const float* wp = &sWB[(ci * 81 + kh * 9 + kw) * 8];
#pragma unroll
        for (int co = 0; co < 8; ++co) {
          acc[0][co] += x0 * wp[co];
          acc[1][co] += x1 * wp[co];
        }
      }
    }
  }

#pragma unroll
  for (int j = 0; j < 2; ++j) {
    const int h = h0 + r0 + 8 * j;
    const int w = w0 + c;
#pragma unroll
    for (int co = 0; co < 8; ++co) {
      float v = acc[j][co];
      if (OUT == 0)
        outF[(((size_t)b * 128 + h) * 128 + w) * 8 + co] = v;
      else
        outBf[((size_t)b * HW + h * 128 + w) * 8 + co] = f2bf(v);
    }
  }
}

// ---------------------------------------------------------------------------
// fused tail (correctness r9-verified; bank conflict FIXED: sX plane stride
// 1057 ≡ 1 mod 32 so per-thread channel writes hit 8 distinct banks).
// 8 ->(9x9 t-conv) 4 ->(9x9 t-conv) 1, then (vin + lam*v)/(1+lam);
// per-block <vin, vout> partial -> atomicAdd den[b]. grid (64,1,8).
// ---------------------------------------------------------------------------
__global__ __launch_bounds__(256) void fused_tail(
    const u16* __restrict__ t8v, const float* __restrict__ w11,
    const float* __restrict__ w10, const float* __restrict__ vin,
    const float* __restrict__ lam, float* __restrict__ vout,
    float* __restrict__ den)
{
  __shared__ float sX[8][1057];
  __shared__ float sT4[4][24 * 25];
  __shared__ float sW1[8 * 81 * 4];
  __shared__ float sW0[4 * 81];
  __shared__ float sRed[256];

  const int tid = threadIdx.x;
  const int b   = blockIdx.z;
  const int h0  = (blockIdx.x >> 3) * 16;
  const int w0  = (blockIdx.x & 7) * 16;

  for (int e = tid; e < 1024; e += 256) {
    int r = e >> 5, c = e & 31;
    int gh = h0 - 8 + r, gw = w0 - 8 + c;
    float v[8];
    if (gh >= 0 && gh < 128 && gw >= 0 && gw < 128) {
      const u16* s = t8v + ((size_t)b * HW + gh * 128 + gw) * 8;
#pragma unroll
      for (int ci = 0; ci < 8; ++ci) v[ci] = bf2f(s[ci]);
    } else {
#pragma unroll
      for (int ci = 0; ci < 8; ++ci) v[ci] = 0.0f;
    }
#pragma unroll
    for (int ci = 0; ci < 8; ++ci) sX[ci][r * 33 + c] = v[ci];
  }
  for (int e = tid; e < 2592; e += 256) {
    int co = e & 3;
    int rest = e >> 2;
    int tap = rest % 81, ci = rest / 81;
    sW1[(ci * 81 + tap) * 4 + co] = w11[(size_t)(ci * 4 + co) * 81 + (80 - tap)];
  }
  for (int e = tid; e < 324; e += 256) {
    int tap = e % 81, ci = e / 81;
    sW0[ci * 81 + tap] = w10[(size_t)ci * 81 + (80 - tap)];
  }
  __syncthreads();

  for (int e = tid; e < 288; e += 256) {
    int r = e / 12, c2 = (e - r * 12) * 2;
    int gh = h0 - 4 + r;
    int gw0 = w0 - 4 + c2;
    float a0[4] = {0, 0, 0, 0}, a1[4] = {0, 0, 0, 0};
    for (int ci = 0; ci < 8; ++ci) {
      for (int kh = 0; kh < 9; ++kh) {
        const float* xb = &sX[ci][(r + kh) * 33 + c2];
#pragma unroll
        for (int kw = 0; kw < 9; ++kw) {
          float x0 = xb[kw], x1 = xb[kw + 1];
          const float* wp = &sW1[(ci * 81 + kh * 9 + kw) * 4];
#pragma unroll
          for (int co = 0; co < 4; ++co) {
            a0[co] += x0 * wp[co];
            a1[co] += x1 * wp[co];
          }
        }
      }
    }
    bool in0 = (gh >= 0 && gh < 128 && gw0 >= 0 && gw0 < 128);
    bool in1 = (gh >= 0 && gh < 128 && (gw0 + 1) >= 0 && (gw0 + 1) < 128);
#pragma unroll
    for (int co = 0; co < 4; ++co) {
      sT4[co][r * 25 + c2]     = in0 ? a0[co] : 0.0f;
      sT4[co][r * 25 + c2 + 1] = in1 ? a1[co] : 0.0f;
    }
  }
  __syncthreads();

  {
    int r = tid >> 4, c = tid & 15;
    float acc = 0.0f;
    for (int ci = 0; ci < 4; ++ci) {
      for (int kh = 0; kh < 9; ++kh) {
        const float* xb = &sT4[ci][(r + kh) * 25 + c];
        const float* wp = &sW0[ci * 81 + kh * 9];
#pragma unroll
        for (int kw = 0; kw < 9; ++kw) acc += xb[kw] * wp[kw];
      }
    }
    size_t o = (size_t)b * HW + (h0 + r) * 128 + (w0 + c);
    float l = lam[b];
    float vi = vin[o];
    float res = (vi + l * acc) / (1.0f + l);
    vout[o] = res;
    sRed[tid] = vi * res;
  }
  __syncthreads();
  for (int st = 128; st > 0; st >>= 1) {
    if (tid < st) sRed[tid] += sRed[tid + st];
    __syncthreads();
  }
  if (tid == 0) atomicAdd(&den[b], sRed[0]);
}

// ---------------------------------------------------------------------------
// helpers
// ---------------------------------------------------------------------------
__global__ void k_scalars(const float* __restrict__ sigma, const float* __restrict__ c_lam,
                          const float* __restrict__ c_scal, float* __restrict__ lam,
                          float* __restrict__ scal) {
  int tid = threadIdx.x;
  if (tid < BATCH) lam[tid] = spline_eval(sigma[tid], c_lam, 53, -1.0f, 51.0f);
  for (int j = tid; j < BATCH * 128; j += 256) {
    int b = j >> 7, chn = j & 127;
    float s = sigma[b];
    scal[j] = expf(spline_eval(s, c_scal + chn * 14, 14, -1.0f, 51.0f)) / (s + 1e-5f);
  }
}

__global__ void k_binit(const float* __restrict__ y, const float* __restrict__ lam,
                        float* __restrict__ bimg, float* __restrict__ x) {
  int i = blockIdx.x * 256 + threadIdx.x;
  int b = i >> 14;
  bimg[i] = y[i] / (1.0f + lam[b]);
  x[i] = 0.0f;
}

// mask for c_k = 0 (bit-exact, r11-verified)
__global__ void k_fillmask(const float* __restrict__ c_sp3, u16* __restrict__ mask_c) {
  u16 hv = f2bf(fminf(fmaxf(c_sp3[0], 0.01f), 1.0f));
  u16 tmp[8];
#pragma unroll
  for (int j = 0; j < 8; ++j) tmp[j] = hv;
  size_t i = ((size_t)blockIdx.x * 256 + threadIdx.x) * 8;
  *(f4v*)(mask_c + i) = *(const f4v*)tmp;
}

// CG init with BtB(0) = 0: r = p = bimg; rn = <bimg,bimg>; den = 0.
__global__ void k_cg0b(const float* __restrict__ bimg, float* __restrict__ r,
                       float* __restrict__ p, float* __restrict__ rn,
                       float* __restrict__ den) {
  __shared__ float s[256];
  int b = blockIdx.x;
  size_t base = (size_t)b << 14;
  float local = 0.0f;
  for (int i = threadIdx.x; i < HW; i += 256) {
    float v = bimg[base + i];
    r[base + i] = v;
    p[base + i] = v;
    local += v * v;
  }
  s[threadIdx.x] = local;
  __syncthreads();
  for (int st = 128; st > 0; st >>= 1) {
    if (threadIdx.x < st) s[threadIdx.x] += s[threadIdx.x + st];
    __syncthreads();
  }
  if (threadIdx.x == 0) { rn[b] = s[0]; den[b] = 0.0f; }
}

// r = bimg - Bp; p = r; rn = <r,r>; den = 0 (clears r0-BtB pollution)
__global__ void k_cg0(const float* __restrict__ bimg, const float* __restrict__ Bp,
                      float* __restrict__ r, float* __restrict__ p,
                      float* __restrict__ rn, float* __restrict__ den) {
  __shared__ float s[256];
  int b = blockIdx.x;
  size_t base = (size_t)b << 14;
  float local = 0.0f;
  for (int i = threadIdx.x; i < HW; i += 256) {
    float v = bimg[base + i] - Bp[base + i];
    r[base + i] = v;
    p[base + i] = v;
    local += v * v;
  }
  s[threadIdx.x] = local;
  __syncthreads();
  for (int st = 128; st > 0; st >>= 1) {
    if (threadIdx.x < st) s[threadIdx.x] += s[threadIdx.x + st];
    __syncthreads();
  }
  if (threadIdx.x == 0) { rn[b] = s[0]; den[b] = 0.0f; }
}

// alpha-update + rn2 reduce + beta + p-update; zeroes den; optional x->xout.
__global__ void k_cg2(float* __restrict__ x, float* __restrict__ r,
                      float* __restrict__ p, const float* __restrict__ Bp,
                      float* __restrict__ rn, float* __restrict__ den,
                      float* __restrict__ xout) {
  __shared__ float s[256];
  int b = blockIdx.x;
  size_t base = (size_t)b << 14;
  float rnb = rn[b];
  bool act = rnb > 1e-6f;
  float alpha = act ? rnb / den[b] : 0.0f;
  float local = 0.0f;
  for (int i = threadIdx.x; i < HW; i += 256) {
    float pv = p[base + i];
    float xv = x[base + i] + alpha * pv;
    x[base + i] = xv;
    if (xout) xout[base + i] = xv;
    float rr = r[base + i] - alpha * Bp[base + i];
    r[base + i] = rr;
    local += rr * rr;
  }
  s[threadIdx.x] = local;
  __syncthreads();
  for (int st = 128; st > 0; st >>= 1) {
    if (threadIdx.x < st) s[threadIdx.x] += s[threadIdx.x + st];
    __syncthreads();
  }
  float rn2 = s[0];
  float beta = act ? rn2 / rnb : 0.0f;
  if (threadIdx.x == 0) { rn[b] = rn2; den[b] = 0.0f; }
  for (int i = threadIdx.x; i < HW; i += 256)
    p[base + i] = r[base + i] + beta * p[base + i];
}

// ---------------------------------------------------------------------------
extern "C" void kernel_launch(void* const* d_in, const int* in_sizes, int n_in_,
                              void* d_out, int out_size, void* d_ws, size_t ws_size,
                              hipStream_t stream) {
  const float* y      = (const float*)d_in[0];
  const float* sigma  = (const float*)d_in[1];
  const float* w1_0   = (const float*)d_in[2];
  const float* w1_1   = (const float*)d_in[3];
  const float* w1_2   = (const float*)d_in[4];
  const float* m1_0   = (const float*)d_in[5];
  const float* m1_1   = (const float*)d_in[6];
  const float* m1_2   = (const float*)d_in[7];
  const float* m2_w   = (const float*)d_in[8];
  const float* m3_w   = (const float*)d_in[9];
  const float* c_sp1  = (const float*)d_in[10];
  const float* c_sp2  = (const float*)d_in[11];
  const float* c_sp3  = (const float*)d_in[12];
  const float* c_lam  = (const float*)d_in[13];
  const float* c_scal = (const float*)d_in[14];
  // n_out = 2, n_in = 6 fixed by setup_inputs

  char* cur = (char*)d_ws;
  auto alloc = [&](size_t bytes) {
    char* p = cur;
    cur += (bytes + 255) & ~(size_t)255;
    return p;
  };

  // weight fragments (~3 MB)
  u16* wA_hi  = (u16*)alloc(86016 * 2);
  u16* wA_lo  = (u16*)alloc(86016 * 2);
  u16* wAm_hi = (u16*)alloc(86016 * 2);
  u16* wAm_lo = (u16*)alloc(86016 * 2);
  u16* wB_hi  = (u16*)alloc(172032 * 2);
  u16* wB_lo  = (u16*)alloc(172032 * 2);
  u16* wC2_hi = (u16*)alloc(196608 * 2);
  u16* wC2_lo = (u16*)alloc(196608 * 2);
  u16* wC3_hi = (u16*)alloc(196608 * 2);
  u16* wC3_lo = (u16*)alloc(196608 * 2);

  // region1 (67.1 MB): mask phase = P1f fp32 NHWC128; CG = big2c bf16 slice-major
  char* region1 = alloc((size_t)16777216 * 4);
  float* P1f   = (float*)region1;
  u16*   big2c = (u16*)region1;
  // mask_c bf16 slice-major (33.5 MB)
  u16* mask_c = (u16*)alloc((size_t)16777216 * 2);
  // region2 (33.6 MB): mask = P2s fp32 x4 batches; CG = part (16.8) + t8v (2)
  char* region2 = alloc((size_t)4 * 128 * 128 * 128 * 4);
  float* P2s  = (float*)region2;
  float* part = (float*)region2;                          // 4 x 1048576 fp32
  u16*   t8v  = (u16*)(region2 + (size_t)1048576 * 4 * 4);
  // region3 (4.2 MB): mask = t8f fp32 NHWC8; CG = t8c bf16 slice-major
  char* region3 = alloc((size_t)1048576 * 4);
  float* t8f = (float*)region3;
  u16*   t8c = (u16*)region3;

  float* bimg = (float*)alloc(131072 * 4);
  float* xbuf = (float*)alloc(131072 * 4);
  float* rbuf = (float*)alloc(131072 * 4);
  float* pbuf = (float*)alloc(131072 * 4);
  float* Bp   = (float*)alloc(131072 * 4);
  float* lam  = (float*)alloc(8 * 4);
  float* scal = (float*)alloc(1024 * 4);
  float* rn   = (float*)alloc(8 * 4);
  float* den  = (float*)alloc(8 * 4);
  // total ~144 MB (r11 passing layout)

  const dim3 blk(256);

  k_prepw<9, 8, 128, 8, 1, 81, 21, false><<<dim3(42), blk, 0, stream>>>(w1_2, wA_hi, wA_lo);
  k_prepw<9, 8, 128, 8, 1, 81, 21, false><<<dim3(42), blk, 0, stream>>>(m1_2, wAm_hi, wAm_lo);
  k_prepw<9, 8, 8, 1, 16, 81, 21, true><<<dim3(84), blk, 0, stream>>>(w1_2, wB_hi, wB_lo);
  k_prepw<3, 128, 128, 8, 16, 9, 3, false><<<dim3(96), blk, 0, stream>>>(m2_w, wC2_hi, wC2_lo);
  k_prepw<3, 128, 128, 8, 16, 9, 3, false><<<dim3(96), blk, 0, stream>>>(m3_w, wC3_hi, wC3_lo);

  k_scalars<<<dim3(1), blk, 0, stream>>>(sigma, c_lam, c_scal, lam, scal);
  k_binit<<<dim3(512), blk, 0, stream>>>(y, lam, bimg, xbuf);

  // CG path: r11 champion + bconvB K-split + fixed fused_tail (fused dot)
  auto BtB = [&](const float* vin, float* vout) {
    fused_fwd<1><<<dim3(32, 1, 8), blk, 0, stream>>>(vin, w1_0, w1_1, nullptr, t8c);
    bconv<9, 1, 81, 21, 2, 8, 1, 3><<<dim3(64, 8, 4), blk, 0, stream>>>(
        t8c, wA_hi, nullptr, big2c, mask_c);
    bconv<9, 16, 81, 21, 1, 1, 4, 5><<<dim3(64, 8, 4), blk, 0, stream>>>(
        big2c, wB_hi, part, nullptr, nullptr);
    k_combine8<<<dim3(512), blk, 0, stream>>>(part, t8v);
    fused_tail<<<dim3(64, 1, 8), blk, 0, stream>>>(t8v, w1_1, w1_0, vin, lam, vout, den);
  };

  // ================= outer 0: c_k = 0 (algebraic, r11-verified) =============
  k_fillmask<<<dim3(8192), blk, 0, stream>>>(c_sp3, mask_c);
  k_cg0b<<<dim3(8), blk, 0, stream>>>(bimg, rbuf, pbuf, rn, den);
  for (int it = 0; it < 6; ++it) {
    BtB(pbuf, Bp);
    k_cg2<<<dim3(8), blk, 0, stream>>>(xbuf, rbuf, pbuf, Bp, rn, den, nullptr);
  }

  // ================= outer 1 =================
  fused_fwd<0><<<dim3(32, 1, 8), blk, 0, stream>>>(xbuf, m1_0, m1_1, t8f, nullptr);
  mconv<9, 8, 1, 81, 21, 16, 4, 2, 8, 1><<<dim3(64, 8, 4), blk, 0, stream>>>(
      t8f, wAm_hi, wAm_lo, P1f, nullptr, c_sp1, nullptr, 0, 0);
  for (int bc = 0; bc < 2; ++bc) {
    mconv<3, 128, 16, 9, 3, 16, 4, 2, 8, 1><<<dim3(64, 4, 4), blk, 0, stream>>>(
        P1f, wC2_hi, wC2_lo, P2s, nullptr, c_sp2, nullptr, bc * 4, 0);
    mconv<3, 128, 16, 9, 3, 16, 4, 2, 8, 2><<<dim3(64, 4, 4), blk, 0, stream>>>(
        P2s, wC3_hi, wC3_lo, nullptr, mask_c, c_sp3, scal, 0, bc * 4);
  }

  BtB(xbuf, Bp);
  k_cg0<<<dim3(8), blk, 0, stream>>>(bimg, Bp, rbuf, pbuf, rn, den);
  for (int it = 0; it < 6; ++it) {
    BtB(pbuf, Bp);
    float* xout = (it == 5) ? (float*)d_out : nullptr;
    k_cg2<<<dim3(8), blk, 0, stream>>>(xbuf, rbuf, pbuf, Bp, rn, den, xout);
  }
}